// Round 10
// baseline (461.810 us; speedup 1.0000x reference)
//
#include <hip/hip_runtime.h>
#include <hip/hip_bf16.h>

// ---------------------------------------------------------------------------
// PCELayer. Expert convs: fp8 implicit GEMM, 1-row blocks (128px x 128co),
// 4 waves, 18 fine pipeline units (cc2 x ky x kx; B=8KB/unit, A=10.25KB per
// 3 units), A/B dbuf = 36.9KB LDS -> 4 blocks/CU (4 waves/SIMD TLP).
// G experts fused per dispatch, XCD k == image k. Post conv: R6 structure.
// ---------------------------------------------------------------------------

typedef __attribute__((ext_vector_type(8))) short bf16x8;
typedef __attribute__((ext_vector_type(4))) float f32x4;
typedef __attribute__((ext_vector_type(2))) float f32x2;
typedef __attribute__((ext_vector_type(8))) unsigned short u16x8;
typedef __attribute__((ext_vector_type(4))) unsigned short u16x4;
typedef __attribute__((ext_vector_type(2))) unsigned int u32x2;
typedef __attribute__((ext_vector_type(2))) int i32x2;
typedef __attribute__((ext_vector_type(2))) long lx2;

__device__ __forceinline__ float b2f(unsigned short u) {
  unsigned int v = ((unsigned int)u) << 16;
  return __builtin_bit_cast(float, v);
}
__device__ __forceinline__ unsigned short f2b(float f) {
  __hip_bfloat16 h = __float2bfloat16(f);
  return __builtin_bit_cast(unsigned short, h);
}
__device__ __forceinline__ float fsilu(float x) {
  float e = __expf(-x);
  return x * __builtin_amdgcn_rcpf(1.f + e);
}
__device__ __forceinline__ void gll16(const void* g, void* l) {
  __builtin_amdgcn_global_load_lds(
      (const __attribute__((address_space(1))) unsigned int*)g,
      (__attribute__((address_space(3))) unsigned int*)l, 16, 0, 0);
}
__device__ __forceinline__ unsigned char f2fp8(float v) {
  return (unsigned char)(__builtin_amdgcn_cvt_pk_fp8_f32(v, v, 0, false) & 0xff);
}

#define PLANE8 8652800ull  // 8*130*130*64 bytes per 64-ci fp8 plane (2 planes)

// ---- router ---------------------------------------------------------------
__global__ void k_router(const float* __restrict__ rw, const float* __restrict__ rb,
                         float* __restrict__ wts) {
  int t = threadIdx.x;
  if (t >= 64) return;
  int py = t >> 3, px = t & 7;
  float cy = (py + 0.5f) / 8.f, cx = (px + 0.5f) / 8.f;
  const float PI = 3.14159265358979323846f;
  float f[16];
#pragma unroll
  for (int k = 0; k < 4; ++k) {
    float fr = (float)(1 << k) * PI;
    f[k] = sinf(cy * fr); f[4 + k] = cosf(cy * fr);
    f[8 + k] = sinf(cx * fr); f[12 + k] = cosf(cx * fr);
  }
  float lg[8], mx = -1e30f;
#pragma unroll
  for (int e = 0; e < 8; ++e) {
    float a = rb[e];
#pragma unroll
    for (int k = 0; k < 16; ++k) a += f[k] * rw[k * 8 + e];
    lg[e] = a; mx = fmaxf(mx, a);
  }
  float s = 0.f;
#pragma unroll
  for (int e = 0; e < 8; ++e) { lg[e] = __expf(lg[e] - mx); s += lg[e]; }
  float inv = 1.f / s;
#pragma unroll
  for (int e = 0; e < 8; ++e) wts[t * 8 + e] = lg[e] * inv;
}

// ---- zero halo borders of xpad (bf16) and xpad8 (2 fp8 planes) -------------
__global__ void k_zborder(unsigned short* __restrict__ xpu,
                          unsigned char* __restrict__ xp8) {
  int idx = blockIdx.x * 256 + threadIdx.x;
  if (idx >= 8 * 516) return;
  int b = idx / 516, pxi = idx - b * 516;
  int r, c;
  if (pxi < 130)      { r = 0;   c = pxi; }
  else if (pxi < 260) { r = 129; c = pxi - 130; }
  else if (pxi < 388) { r = pxi - 260 + 1; c = 0; }
  else                { r = pxi - 388 + 1; c = 129; }
  size_t pix = (size_t)(b * 130 + r) * 130 + c;
  unsigned short* p = xpu + pix * 128;
#pragma unroll
  for (int j = 0; j < 16; ++j) *(u16x8*)(p + j * 8) = (u16x8)0;
#pragma unroll
  for (int cc = 0; cc < 2; ++cc) {
    f32x4* q = (f32x4*)(xp8 + cc * PLANE8 + pix * 64);
#pragma unroll
    for (int j = 0; j < 4; ++j) q[j] = (f32x4)0.f;
  }
}

// ---- x (NCHW f32) -> xpad bf16 [pix][128] + xpad8 fp8 dual-K perm planes ---
__global__ void k_build_xpad(const float* __restrict__ x, __hip_bfloat16* __restrict__ xp,
                             unsigned char* __restrict__ xp8) {
  int bx = blockIdx.x;
  int wb = bx & 1, cib = (bx >> 1) & 1;
  int h = (bx >> 2) & 127, b = bx >> 9;
  int w0 = wb * 64, ci0 = cib * 64;
  __shared__ float t[64][65];
  int tid = threadIdx.x;
#pragma unroll
  for (int r = 0; r < 16; ++r) {
    int idx = r * 256 + tid;
    int i = idx >> 6, j = idx & 63;  // i: ci, j: w
    t[i][j] = x[(((size_t)b * 128 + ci0 + i) * 128 + h) * 128 + w0 + j];
  }
  __syncthreads();
  unsigned short* xpu = (unsigned short*)xp;
#pragma unroll
  for (int r = 0; r < 2; ++r) {
    int s = r * 256 + tid;          // 512 slots: 64 px x 8 ci-groups
    int px = s >> 3, cg = s & 7;
    size_t pixbase = ((size_t)b * 130 + h + 1) * 130 + (w0 + px + 1);
    float v[8];
    u16x8 bv;
#pragma unroll
    for (int k = 0; k < 8; ++k) { v[k] = t[cg * 8 + k][px]; bv[k] = f2b(v[k]); }
    int ci = ci0 + cg * 8;
    *(u16x8*)(xpu + pixbase * 128 + ci) = bv;
    int pl = ci >> 6, cl = ci & 63;
    int kg = (cl >> 3) & 3, c = cl >> 5;
    int pk0 = __builtin_amdgcn_cvt_pk_fp8_f32(v[0], v[1], 0, false);
    pk0 = __builtin_amdgcn_cvt_pk_fp8_f32(v[2], v[3], pk0, true);
    int pk1 = __builtin_amdgcn_cvt_pk_fp8_f32(v[4], v[5], 0, false);
    pk1 = __builtin_amdgcn_cvt_pk_fp8_f32(v[6], v[7], pk1, true);
    i32x2 pk = {pk0, pk1};
    *(i32x2*)(xp8 + (size_t)pl * PLANE8 + pixbase * 64 + kg * 16 + c * 8) = pk;
  }
}

// ---- post weights [co][ci][3][3] f32 -> [cc][tap][co][32ci] bf16 ----------
__global__ void k_build_w(const float* __restrict__ src, __hip_bfloat16* __restrict__ dst) {
  int o = blockIdx.x * 256 + threadIdx.x;
  if (o >= 147456) return;
  int cl = o & 31, co = (o >> 5) & 127;
  int r9 = o >> 12;  // 0..35
  int tp = r9 % 9, cc = r9 / 9;
  int ci = cc * 32 + cl;
  ((unsigned short*)dst)[o] = f2b(src[((size_t)co * 128 + ci) * 9 + tp]);
}

// ---- expert weights -> [e][cc2][tap][co][64B dual-K perm] fp8 --------------
__global__ void k_build_w8(const float* __restrict__ src, unsigned char* __restrict__ dst) {
  int o = blockIdx.x * 256 + threadIdx.x;
  if (o >= 1179648) return;
  int e = o / 147456;
  int r = o - e * 147456;
  int cc2 = r / 73728;
  int r2 = r - cc2 * 73728;
  int tp = r2 >> 13;
  int r3 = r2 & 8191;
  int co = r3 >> 6, p = r3 & 63;
  int kg = p >> 4, c = (p >> 3) & 1, j = p & 7;
  int ci = cc2 * 64 + c * 32 + kg * 8 + j;
  dst[o] = f2fp8(src[(((size_t)e * 128 + co) * 128 + ci) * 9 + tp]);
}

// ---- expert conv3x3 fp8, G experts fused: 128px(1 row) x 128co per block --
// 18 units (cc2 x ky x kx). A dbuf 2x10240 @ 0; B dbuf 2x8192 @ 20480.
// LDS 36864 -> 4 blocks/CU (16 waves). XCD k == image k.
template <int G>
__global__ __launch_bounds__(256, 4) void k_conv8(
    const unsigned char* __restrict__ xp8, const unsigned char* __restrict__ wt8,
    unsigned char* __restrict__ out8base, float* __restrict__ partials) {
  __shared__ __align__(16) char smem[36864];
  const int cpx = G * 128;
  const int nid = (blockIdx.x & 7) * cpx + (blockIdx.x >> 3);
  const int eg = nid & (G - 1);
  const int t0 = nid / G;
  const int b = t0 >> 7, h0 = t0 & 127;
  const unsigned char* wt = wt8 + (size_t)eg * 147456;
  unsigned char* out8 = out8base + (size_t)eg * 16777216ull;

  const int tid = threadIdx.x;
  const int lane = tid & 63, wid = tid >> 6;
  const int wm = wid >> 1, wn = wid & 1;
  const int rl = lane & 15, kg = lane >> 4;

  // LDS read offsets
  int aoff[3][4];  // [kx][mb], relative to A buffer base
  int boff[4];     // [nb], relative to B buffer base
#pragma unroll
  for (int mb = 0; mb < 4; ++mb) {
    int col = wm * 64 + mb * 16 + rl;
#pragma unroll
    for (int kx = 0; kx < 3; ++kx) {
      int px = col + kx;
      aoff[kx][mb] = px * 64 + (kg ^ ((px >> 1) & 3)) * 16;
    }
  }
#pragma unroll
  for (int nb = 0; nb < 4; ++nb) {
    int co = wn * 64 + nb * 16 + rl;
    boff[nb] = (co * 4 + (kg ^ ((co >> 1) & 3))) * 16;
  }

  // single per-thread staging offset (group term is an imm multiple of 4096)
  const int stg = (tid >> 2) * 64 + ((tid & 3) ^ ((tid >> 3) & 3)) * 16;
  const int ldso = tid * 16;

  f32x4 acc[4][4] = {};

  // A row (cc2,ky) -> Abuf[ab]: 640 slots (2.5 iters)
#define STGA(ab, cc2_, ky_)                                                    \
  {                                                                            \
    const unsigned char* abase =                                               \
        xp8 + (size_t)(cc2_)*PLANE8 + (size_t)(b * 130 + h0 + (ky_)) * 8320;   \
    char* D = smem + (ab)*10240;                                               \
    gll16(abase + stg, D + ldso);                                              \
    gll16(abase + stg + 4096, D + ldso + 4096);                                \
    if (tid < 128) gll16(abase + stg + 8192, D + ldso + 8192);                 \
  }
  // B tap (cc2, tap) -> Bbuf[bb]: 512 slots (2 iters)
#define STGB(bb, cc2_, tap_)                                                   \
  {                                                                            \
    const unsigned char* bbase = wt + (cc2_)*73728 + (tap_)*8192;              \
    char* D = smem + 20480 + (bb)*8192;                                        \
    gll16(bbase + stg, D + ldso);                                              \
    gll16(bbase + stg + 4096, D + ldso + 4096);                                \
  }

  STGA(0, 0, 0);
  STGB(0, 0, 0);
#pragma unroll
  for (int u = 0; u < 18; ++u) {
    __syncthreads();
    if (u + 1 < 18) {
      const int un = u + 1;
      const int cc2n = un / 9, rn = un % 9;
      STGB(un & 1, cc2n, rn);
      if (un % 3 == 0) {
        const int a3 = un / 3;               // A index: (cc2, ky)
        STGA(a3 & 1, a3 / 3, a3 % 3);
      }
    }
    const int a3 = u / 3, kx = u % 3;
    const char* Al = smem + (a3 & 1) * 10240;
    const char* Bl = smem + 20480 + (u & 1) * 8192;
    lx2 av[4], bv[4];
#pragma unroll
    for (int mb = 0; mb < 4; ++mb) av[mb] = *(const lx2*)(Al + aoff[kx][mb]);
#pragma unroll
    for (int nb = 0; nb < 4; ++nb) bv[nb] = *(const lx2*)(Bl + boff[nb]);
#pragma unroll
    for (int c = 0; c < 2; ++c)
#pragma unroll
      for (int mb = 0; mb < 4; ++mb)
#pragma unroll
        for (int nb = 0; nb < 4; ++nb)
          acc[mb][nb] = __builtin_amdgcn_mfma_f32_16x16x32_fp8_fp8(
              bv[nb][c], av[mb][c], acc[mb][nb], 0, 0, 0);
  }
#undef STGA
#undef STGB

  // epilogue: fp8 pack + 4B stores, per-block GN partials
  float sv[4] = {0, 0, 0, 0}, qv[4] = {0, 0, 0, 0};
#pragma unroll
  for (int mb = 0; mb < 4; ++mb) {
    int px = wm * 64 + mb * 16 + rl;
    size_t base = (((size_t)b * 128 + h0) * 128 + px) * 128;
#pragma unroll
    for (int nb = 0; nb < 4; ++nb) {
      int co0 = wn * 64 + nb * 16 + kg * 4;
      f32x4 v = acc[mb][nb];
#pragma unroll
      for (int j = 0; j < 4; ++j) { sv[nb] += v[j]; qv[nb] += v[j] * v[j]; }
      int pk = __builtin_amdgcn_cvt_pk_fp8_f32(v[0], v[1], 0, false);
      pk = __builtin_amdgcn_cvt_pk_fp8_f32(v[2], v[3], pk, true);
      *(int*)(out8 + base + co0) = pk;
    }
  }
  __syncthreads();
  float* sg = (float*)smem;
  if (tid < 16) sg[tid] = 0.f;
  __syncthreads();
#pragma unroll
  for (int nb = 0; nb < 4; ++nb) {
    float a = sv[nb], q = qv[nb];
#pragma unroll
    for (int o = 32; o > 0; o >>= 1) { a += __shfl_down(a, o); q += __shfl_down(q, o); }
    if (lane == 0) {
      int g = wn * 4 + nb;
      atomicAdd(&sg[g * 2 + 0], a);
      atomicAdd(&sg[g * 2 + 1], q);
    }
  }
  __syncthreads();
  if (tid < 16)
    partials[(((size_t)(eg * 8 + b)) * 128 + h0) * 16 + tid] = sg[tid];
}

// ---- post conv3x3 bf16 (R9 structure, unchanged) ----------------------------
__global__ __launch_bounds__(256, 2) void k_conv(
    const unsigned short* __restrict__ xpu, const unsigned short* __restrict__ wtu,
    unsigned short* __restrict__ outu, float* __restrict__ partials) {
  __shared__ __align__(16) char smem[69632];
  const int bx0 = blockIdx.x;
  const int nid = (bx0 & 7) * 128 + (bx0 >> 3);
  const int b = nid >> 7, h0 = nid & 127;
  const int tid = threadIdx.x;
  const int lane = tid & 63, wid = tid >> 6;
  const int wm = wid >> 1, wn = wid & 1;
  const int rl = lane & 15, kg = lane >> 4;

  int aoff[3][4], boff[3][4];
#pragma unroll
  for (int mb = 0; mb < 4; ++mb) {
    int w = wm * 64 + mb * 16 + rl;
#pragma unroll
    for (int kx = 0; kx < 3; ++kx) {
      int px = w + kx;
      aoff[kx][mb] = (px * 4 + (kg ^ ((px >> 1) & 3))) * 16;
    }
  }
#pragma unroll
  for (int kx = 0; kx < 3; ++kx)
#pragma unroll
    for (int nb = 0; nb < 4; ++nb) {
      int co = wn * 64 + nb * 16 + rl;
      boff[kx][nb] = 10240 + ((kx * 128 + co) * 4 + (kg ^ ((co >> 1) & 3))) * 16;
    }

  int asoff[3], aloff[3];
#pragma unroll
  for (int it = 0; it < 3; ++it) {
    int s = it * 256 + tid;
    int px = s >> 2, q = s & 3;
    asoff[it] = px * 256 + (q ^ ((px >> 1) & 3)) * 16;
    aloff[it] = s * 16;
  }
  int bsoff[6], bloff[6];
#pragma unroll
  for (int jt = 0; jt < 6; ++jt) {
    int s2 = jt * 256 + tid;
    int t3 = s2 >> 9;
    int r3 = s2 & 511;
    int co = r3 >> 2, q = r3 & 3;
    int qg = q ^ ((co >> 1) & 3);
    bsoff[jt] = t3 * 8192 + co * 64 + qg * 16;
    bloff[jt] = 10240 + s2 * 16;
  }

  f32x4 acc[4][4] = {};
  const char* xpb = (const char*)xpu;
  const char* wtb = (const char*)wtu;

#define STAGE(bi, u)                                                          \
  {                                                                           \
    const int cc_ = (u) / 3, ky_ = (u) % 3;                                   \
    char* D = smem + (bi) * 34816;                                            \
    const char* abase = xpb + (size_t)(b * 130 + h0 + ky_) * 33280 + cc_ * 64;\
    const char* bbase = wtb + cc_ * 73728 + ky_ * 24576;                      \
    _Pragma("unroll")                                                         \
    for (int it = 0; it < 2; ++it)                                            \
      gll16(abase + asoff[it], D + aloff[it]);                                \
    if (tid < 128) gll16(abase + asoff[2], D + aloff[2]);                     \
    _Pragma("unroll")                                                         \
    for (int jt = 0; jt < 6; ++jt)                                            \
      gll16(bbase + bsoff[jt], D + bloff[jt]);                                \
  }

  STAGE(0, 0);
  for (int u = 0; u < 12; ++u) {
    const int cur = u & 1;
    __syncthreads();
    if (u + 1 < 12) STAGE(cur ^ 1, u + 1);
    char* Al = smem + cur * 34816;
#pragma unroll
    for (int kx = 0; kx < 3; ++kx) {
      bf16x8 aF[4], bF[4];
#pragma unroll
      for (int mb = 0; mb < 4; ++mb) aF[mb] = *(const bf16x8*)(Al + aoff[kx][mb]);
#pragma unroll
      for (int nb = 0; nb < 4; ++nb) bF[nb] = *(const bf16x8*)(Al + boff[kx][nb]);
#pragma unroll
      for (int mb = 0; mb < 4; ++mb)
#pragma unroll
        for (int nb = 0; nb < 4; ++nb)
          acc[mb][nb] = __builtin_amdgcn_mfma_f32_16x16x32_bf16(
              bF[nb], aF[mb], acc[mb][nb], 0, 0, 0);
    }
  }
#undef STAGE

  float sv[4] = {0, 0, 0, 0}, qv[4] = {0, 0, 0, 0};
#pragma unroll
  for (int mb = 0; mb < 4; ++mb) {
    int w = wm * 64 + mb * 16 + rl;
    size_t base = (((size_t)b * 128 + h0) * 128 + w) * 128;
#pragma unroll
    for (int nb = 0; nb < 4; ++nb) {
      int co0 = wn * 64 + nb * 16 + kg * 4;
      u16x4 pk;
#pragma unroll
      for (int j = 0; j < 4; ++j) {
        float v = acc[mb][nb][j];
        pk[j] = f2b(v);
        sv[nb] += v; qv[nb] += v * v;
      }
      *(u16x4*)(outu + base + co0) = pk;
    }
  }
  __syncthreads();
  float* sg = (float*)smem;
  if (tid < 16) sg[tid] = 0.f;
  __syncthreads();
#pragma unroll
  for (int nb = 0; nb < 4; ++nb) {
    float a = sv[nb], q = qv[nb];
#pragma unroll
    for (int o = 32; o > 0; o >>= 1) { a += __shfl_down(a, o); q += __shfl_down(q, o); }
    if (lane == 0) {
      int g = wn * 4 + nb;
      atomicAdd(&sg[g * 2 + 0], a);
      atomicAdd(&sg[g * 2 + 1], q);
    }
  }
  __syncthreads();
  if (tid < 16) partials[(size_t)nid * 16 + tid] = sg[tid];
}

// ---- reduce per-block partials [set][b][nper][16] -> stats[set][128] ------
__global__ void k_redstats(const float* __restrict__ partials, float* __restrict__ stats,
                           int nper) {
  int set = blockIdx.x;
  const float* p = partials + (size_t)set * 8 * nper * 16;
  float* st = stats + set * 128;
  int t = threadIdx.x;
  int o = t >> 2, j = t & 3;
  int b = o >> 4, slot = o & 15;
  int chunk = nper >> 2;
  float s = 0.f;
  for (int i = j * chunk; i < (j + 1) * chunk; ++i)
    s += p[((size_t)b * nper + i) * 16 + slot];
  s += __shfl_xor(s, 1);
  s += __shfl_xor(s, 2);
  if (j == 0) st[o] = s;
}

// ---- reduce merge partials (8192 x 16) -> stats2 --------------------------
__global__ void k_redstats2(const float* __restrict__ p2, float* __restrict__ st) {
  int o = blockIdx.x;
  int b = o >> 4, slot = o & 15;
  float s = 0.f;
  for (int i = threadIdx.x; i < 1024; i += 256)
    s += p2[((size_t)b * 1024 + i) * 16 + slot];
#pragma unroll
  for (int off = 32; off > 0; off >>= 1) s += __shfl_down(s, off);
  __shared__ float wsm[4];
  int lane = threadIdx.x & 63, wv = threadIdx.x >> 6;
  if (lane == 0) wsm[wv] = s;
  __syncthreads();
  if (threadIdx.x == 0) st[o] = wsm[0] + wsm[1] + wsm[2] + wsm[3];
}

// ---- merge NEXP fp8 experts ------------------------------------------------
template <int NEXP>
__global__ void k_merge(const unsigned char* __restrict__ c0,
                        const unsigned char* __restrict__ c1,
                        const unsigned char* __restrict__ c2,
                        const unsigned char* __restrict__ c3,
                        const float* __restrict__ st, const float* __restrict__ eg,
                        const float* __restrict__ eb, const float* __restrict__ wts,
                        unsigned short* __restrict__ merged,
                        const unsigned short* __restrict__ xp,
                        float* __restrict__ partials2, int e0, int flags) {
  __shared__ float sg[16];
  int tid = threadIdx.x;
  if (tid < 16) sg[tid] = 0.f;
  __syncthreads();
  size_t idx = ((size_t)blockIdx.x * 256 + tid) * 8;
  int co0 = (int)(idx & 127);
  size_t pix = idx >> 7;
  int w = (int)(pix & 127), h = (int)((pix >> 7) & 127), b = (int)(pix >> 14);
  int g = co0 >> 4;
  const float cnt = 16.f * 128.f * 128.f;
  int patch = (h >> 4) * 8 + (w >> 4);
  const unsigned char* cs[4] = {c0, c1, c2, c3};
  float a[8] = {0, 0, 0, 0, 0, 0, 0, 0};
#pragma unroll
  for (int k = 0; k < NEXP; ++k) {
    int e = e0 + k;
    float mean = st[e * 128 + (b * 8 + g) * 2] / cnt;
    float var = st[e * 128 + (b * 8 + g) * 2 + 1] / cnt - mean * mean;
    float rstd = rsqrtf(var + 1e-5f);
    float we = wts[patch * 8 + e];
    f32x4 g0 = *(const f32x4*)(eg + e * 128 + co0);
    f32x4 g1 = *(const f32x4*)(eg + e * 128 + co0 + 4);
    f32x4 b0 = *(const f32x4*)(eb + e * 128 + co0);
    f32x4 b1 = *(const f32x4*)(eb + e * 128 + co0 + 4);
    u32x2 cv = *(const u32x2*)(cs[k] + idx);
    f32x2 d0 = __builtin_amdgcn_cvt_pk_f32_fp8(cv[0], false);
    f32x2 d1 = __builtin_amdgcn_cvt_pk_f32_fp8(cv[0], true);
    f32x2 d2 = __builtin_amdgcn_cvt_pk_f32_fp8(cv[1], false);
    f32x2 d3 = __builtin_amdgcn_cvt_pk_f32_fp8(cv[1], true);
    float d[8] = {d0[0], d0[1], d1[0], d1[1], d2[0], d2[1], d3[0], d3[1]};
#pragma unroll
    for (int i = 0; i < 8; ++i) {
      float gi = (i < 4) ? g0[i] : g1[i - 4];
      float bi = (i < 4) ? b0[i] : b1[i - 4];
      float A = rstd * gi;
      float B = bi - mean * A;
      a[i] += we * fsilu(d[i] * A + B);
    }
  }
  if (flags & 1) {
    u16x8 mv = *(const u16x8*)(merged + idx);
#pragma unroll
    for (int i = 0; i < 8; ++i) a[i] += b2f(mv[i]);
  }
  u16x8 out;
  float s = 0.f, q = 0.f;
  if (flags & 2) {
    const unsigned short* xr =
        xp + (((size_t)b * 130 + h + 1) * 130 + (w + 1)) * 128 + co0;
    u16x8 xv = *(const u16x8*)xr;
#pragma unroll
    for (int i = 0; i < 8; ++i) {
      a[i] += b2f(xv[i]);
      out[i] = f2b(a[i]);
      float rv = b2f(out[i]);
      s += rv; q += rv * rv;
    }
  } else {
#pragma unroll
    for (int i = 0; i < 8; ++i) out[i] = f2b(a[i]);
  }
  *(u16x8*)(merged + idx) = out;
  if (flags & 2) {
    atomicAdd(&sg[g * 2 + 0], s);
    atomicAdd(&sg[g * 2 + 1], q);
    __syncthreads();
    if (tid < 16) partials2[(size_t)blockIdx.x * 16 + tid] = sg[tid];
  }
}

// ---- y = x + gamma*silu(gn(M)); bf16, in place into xpad -------------------
__global__ void k_ypass(const unsigned short* __restrict__ merged,
                        unsigned short* __restrict__ xp,
                        const float* __restrict__ st, const float* __restrict__ mg,
                        const float* __restrict__ mbv, const float* __restrict__ gptr) {
  size_t idx = ((size_t)blockIdx.x * 256 + threadIdx.x) * 8;
  int co0 = (int)(idx & 127);
  size_t pix = idx >> 7;
  int w = (int)(pix & 127), h = (int)((pix >> 7) & 127), b = (int)(pix >> 14);
  int g = co0 >> 4;
  const float cnt = 16.f * 128.f * 128.f;
  float mean = st[(b * 8 + g) * 2] / cnt;
  float var = st[(b * 8 + g) * 2 + 1] / cnt - mean * mean;
  float rstd = rsqrtf(var + 1e-5f);
  float gm = gptr[0];
  unsigned short* xr = xp + (((size_t)b * 130 + h + 1) * 130 + (w + 1)) * 128 + co0;
  u16x8 xv = *(const u16x8*)xr;
  u16x8 mv = *(const u16x8*)(merged + idx);
  u16x8 yv;
#pragma unroll
  for (int i = 0; i < 8; ++i) {
    float xf = b2f(xv[i]);
    float M = b2f(mv[i]);
    float xn = (M - mean) * rstd * mg[co0 + i] + mbv[co0 + i];
    yv[i] = f2b(xf + gm * fsilu(xn));
  }
  *(u16x8*)xr = yv;
}

// ---- final: out = silu(gn3(conv3)), NHWC bf16 -> NCHW f32 ------------------
__global__ void k_final(const __hip_bfloat16* __restrict__ conv, const float* __restrict__ st,
                        const float* __restrict__ pg, const float* __restrict__ pb,
                        float* __restrict__ out) {
  int bx = blockIdx.x;
  int wb = bx & 1, h = (bx >> 1) & 127, b = bx >> 8;
  int w0 = wb * 64;
  __shared__ float t[64][129];
  int tid = threadIdx.x;
  const float cnt = 16.f * 128.f * 128.f;
  const unsigned short* cu = (const unsigned short*)conv;
#pragma unroll
  for (int r = 0; r < 32; ++r) {
    int e2 = r * 256 + tid;
    int co = e2 & 127, wl = e2 >> 7;
    int g = co >> 4;
    float mean = st[(b * 8 + g) * 2] / cnt;
    float var = st[(b * 8 + g) * 2 + 1] / cnt - mean * mean;
    float rstd = rsqrtf(var + 1e-5f);
    float v = b2f(cu[(((size_t)b * 128 + h) * 128 + w0 + wl) * 128 + co]);
    float xn = (v - mean) * rstd * pg[co] + pb[co];
    t[wl][co] = fsilu(xn);
  }
  __syncthreads();
#pragma unroll
  for (int r = 0; r < 8; ++r) {
    int f = r * 256 + tid;
    int jb = f & 15, co = f >> 4;
    f32x4 o;
#pragma unroll
    for (int j = 0; j < 4; ++j) o[j] = t[jb * 4 + j][co];
    *(f32x4*)&out[(((size_t)b * 128 + co) * 128 + h) * 128 + w0 + jb * 4] = o;
  }
}

// ---------------------------------------------------------------------------
extern "C" void kernel_launch(void* const* d_in, const int* in_sizes, int n_in,
                              void* d_out, int out_size, void* d_ws, size_t ws_size,
                              hipStream_t stream) {
  const float* x        = (const float*)d_in[0];
  const float* expert_w = (const float*)d_in[1];
  const float* expert_g = (const float*)d_in[2];
  const float* expert_b = (const float*)d_in[3];
  const float* router_w = (const float*)d_in[4];
  const float* router_b = (const float*)d_in[5];
  const float* merge_g  = (const float*)d_in[6];
  const float* merge_b  = (const float*)d_in[7];
  const float* gamma    = (const float*)d_in[8];
  const float* post_w   = (const float*)d_in[9];
  const float* post_g   = (const float*)d_in[10];
  const float* post_b   = (const float*)d_in[11];

  char* ws = (char*)d_ws;
  float* wts            = (float*)(ws + 0);                  // 2048
  float* stats          = (float*)(ws + 2048);               // 5120
  float* partials       = (float*)(ws + 8192);               // 262144
  float* partials2      = (float*)(ws + 270336);             // 524288
  unsigned short* wtbp  = (unsigned short*)(ws + 794624);    // 294912
  unsigned char* wtb8   = (unsigned char*)(ws + 1089536);    // 1179648
  unsigned short* xpad  = (unsigned short*)(ws + 2269184);   // 34611200 (+8192 slack)
  unsigned char* xpad8  = (unsigned char*)(ws + 36888576);   // 17305600 (+4096 slack)
  const size_t BUFS = 54198272ull;
  const size_t FB = 16777216ull;
  const size_t NEED2 = BUFS + 2 * FB + 33554432ull;
  const size_t NEED4 = BUFS + 4 * FB + 33554432ull;
  int nbuf = (ws_size >= NEED4) ? 4 : 2;
  unsigned char* bufs0 = (unsigned char*)(ws + BUFS);
  unsigned short* merged = (unsigned short*)(ws + BUFS + (size_t)nbuf * FB);
  unsigned short* pbuf = (unsigned short*)(ws + BUFS);  // post conv out (reuse)
  if (ws_size < NEED2) {
    hipMemsetAsync(d_out, 0, (size_t)out_size * 4, stream);
    return;
  }

  k_zborder<<<17, 256, 0, stream>>>(xpad, xpad8);
  k_router<<<1, 64, 0, stream>>>(router_w, router_b, wts);
  k_build_xpad<<<4096, 256, 0, stream>>>(x, (__hip_bfloat16*)xpad, xpad8);
  k_build_w<<<576, 256, 0, stream>>>(post_w, (__hip_bfloat16*)wtbp);
  k_build_w8<<<4608, 256, 0, stream>>>(expert_w, wtb8);

  if (nbuf == 4) {
    for (int p = 0; p < 2; ++p) {
      k_conv8<4><<<4096, 256, 0, stream>>>(xpad8, wtb8 + (size_t)(p * 4) * 147456,
                                           bufs0, partials);
      k_redstats<<<4, 512, 0, stream>>>(partials, stats + p * 4 * 128, 128);
      int flags = (p > 0 ? 1 : 0) | (p == 1 ? 2 : 0);
      k_merge<4><<<8192, 256, 0, stream>>>(bufs0, bufs0 + FB, bufs0 + 2 * FB,
                                           bufs0 + 3 * FB, stats, expert_g, expert_b,
                                           wts, merged, xpad, partials2, p * 4, flags);
    }
  } else {
    for (int p = 0; p < 4; ++p) {
      k_conv8<2><<<2048, 256, 0, stream>>>(xpad8, wtb8 + (size_t)(p * 2) * 147456,
                                           bufs0, partials);
      k_redstats<<<2, 512, 0, stream>>>(partials, stats + p * 2 * 128, 128);
      int flags = (p > 0 ? 1 : 0) | (p == 3 ? 2 : 0);
      k_merge<2><<<8192, 256, 0, stream>>>(bufs0, bufs0 + FB, bufs0, bufs0 + FB,
                                           stats, expert_g, expert_b, wts, merged,
                                           xpad, partials2, p * 2, flags);
    }
  }
  k_redstats2<<<128, 256, 0, stream>>>(partials2, stats + 8 * 128);
  k_ypass<<<8192, 256, 0, stream>>>(merged, xpad, stats + 8 * 128, merge_g, merge_b, gamma);
  k_conv<<<1024, 256, 0, stream>>>(xpad, wtbp, pbuf, partials);
  k_redstats<<<1, 512, 0, stream>>>(partials, stats + 9 * 128, 128);
  k_final<<<2048, 256, 0, stream>>>((const __hip_bfloat16*)pbuf, stats + 9 * 128,
                                    post_g, post_b, (float*)d_out);
}

// Round 11
// 448.337 us; speedup vs baseline: 1.0301x; 1.0301x over previous
//
#include <hip/hip_runtime.h>
#include <hip/hip_bf16.h>

// ---------------------------------------------------------------------------
// PCELayer. Expert convs: fp8 implicit GEMM (R9 proven structure: 2-row
// 256px x 128co blocks, 8 waves, 6 dbuf units of 45KB, 0 bank conflicts,
// no spill) + T5 setprio. Post conv ported onto the same skeleton (bf16,
// 12 units). G experts fused per dispatch, XCD k == image k.
// ---------------------------------------------------------------------------

typedef __attribute__((ext_vector_type(8))) short bf16x8;
typedef __attribute__((ext_vector_type(4))) float f32x4;
typedef __attribute__((ext_vector_type(2))) float f32x2;
typedef __attribute__((ext_vector_type(8))) unsigned short u16x8;
typedef __attribute__((ext_vector_type(4))) unsigned short u16x4;
typedef __attribute__((ext_vector_type(2))) unsigned int u32x2;
typedef __attribute__((ext_vector_type(2))) int i32x2;
typedef __attribute__((ext_vector_type(2))) long lx2;

__device__ __forceinline__ float b2f(unsigned short u) {
  unsigned int v = ((unsigned int)u) << 16;
  return __builtin_bit_cast(float, v);
}
__device__ __forceinline__ unsigned short f2b(float f) {
  __hip_bfloat16 h = __float2bfloat16(f);
  return __builtin_bit_cast(unsigned short, h);
}
__device__ __forceinline__ float fsilu(float x) {
  float e = __expf(-x);
  return x * __builtin_amdgcn_rcpf(1.f + e);
}
__device__ __forceinline__ void gll16(const void* g, void* l) {
  __builtin_amdgcn_global_load_lds(
      (const __attribute__((address_space(1))) unsigned int*)g,
      (__attribute__((address_space(3))) unsigned int*)l, 16, 0, 0);
}
__device__ __forceinline__ unsigned char f2fp8(float v) {
  return (unsigned char)(__builtin_amdgcn_cvt_pk_fp8_f32(v, v, 0, false) & 0xff);
}

#define PLANE8 8652800ull  // 8*130*130*64 bytes per 64-ci fp8 plane (2 planes)

// ---- router ---------------------------------------------------------------
__global__ void k_router(const float* __restrict__ rw, const float* __restrict__ rb,
                         float* __restrict__ wts) {
  int t = threadIdx.x;
  if (t >= 64) return;
  int py = t >> 3, px = t & 7;
  float cy = (py + 0.5f) / 8.f, cx = (px + 0.5f) / 8.f;
  const float PI = 3.14159265358979323846f;
  float f[16];
#pragma unroll
  for (int k = 0; k < 4; ++k) {
    float fr = (float)(1 << k) * PI;
    f[k] = sinf(cy * fr); f[4 + k] = cosf(cy * fr);
    f[8 + k] = sinf(cx * fr); f[12 + k] = cosf(cx * fr);
  }
  float lg[8], mx = -1e30f;
#pragma unroll
  for (int e = 0; e < 8; ++e) {
    float a = rb[e];
#pragma unroll
    for (int k = 0; k < 16; ++k) a += f[k] * rw[k * 8 + e];
    lg[e] = a; mx = fmaxf(mx, a);
  }
  float s = 0.f;
#pragma unroll
  for (int e = 0; e < 8; ++e) { lg[e] = __expf(lg[e] - mx); s += lg[e]; }
  float inv = 1.f / s;
#pragma unroll
  for (int e = 0; e < 8; ++e) wts[t * 8 + e] = lg[e] * inv;
}

// ---- zero halo borders of xpad (bf16) and xpad8 (2 fp8 planes) -------------
__global__ void k_zborder(unsigned short* __restrict__ xpu,
                          unsigned char* __restrict__ xp8) {
  int idx = blockIdx.x * 256 + threadIdx.x;
  if (idx >= 8 * 516) return;
  int b = idx / 516, pxi = idx - b * 516;
  int r, c;
  if (pxi < 130)      { r = 0;   c = pxi; }
  else if (pxi < 260) { r = 129; c = pxi - 130; }
  else if (pxi < 388) { r = pxi - 260 + 1; c = 0; }
  else                { r = pxi - 388 + 1; c = 129; }
  size_t pix = (size_t)(b * 130 + r) * 130 + c;
  unsigned short* p = xpu + pix * 128;
#pragma unroll
  for (int j = 0; j < 16; ++j) *(u16x8*)(p + j * 8) = (u16x8)0;
#pragma unroll
  for (int cc = 0; cc < 2; ++cc) {
    f32x4* q = (f32x4*)(xp8 + cc * PLANE8 + pix * 64);
#pragma unroll
    for (int j = 0; j < 4; ++j) q[j] = (f32x4)0.f;
  }
}

// ---- x (NCHW f32) -> xpad bf16 [pix][128] + xpad8 fp8 dual-K perm planes ---
__global__ void k_build_xpad(const float* __restrict__ x, __hip_bfloat16* __restrict__ xp,
                             unsigned char* __restrict__ xp8) {
  int bx = blockIdx.x;
  int wb = bx & 1, cib = (bx >> 1) & 1;
  int h = (bx >> 2) & 127, b = bx >> 9;
  int w0 = wb * 64, ci0 = cib * 64;
  __shared__ float t[64][65];
  int tid = threadIdx.x;
#pragma unroll
  for (int r = 0; r < 16; ++r) {
    int idx = r * 256 + tid;
    int i = idx >> 6, j = idx & 63;  // i: ci, j: w
    t[i][j] = x[(((size_t)b * 128 + ci0 + i) * 128 + h) * 128 + w0 + j];
  }
  __syncthreads();
  unsigned short* xpu = (unsigned short*)xp;
#pragma unroll
  for (int r = 0; r < 2; ++r) {
    int s = r * 256 + tid;          // 512 slots: 64 px x 8 ci-groups
    int px = s >> 3, cg = s & 7;
    size_t pixbase = ((size_t)b * 130 + h + 1) * 130 + (w0 + px + 1);
    float v[8];
    u16x8 bv;
#pragma unroll
    for (int k = 0; k < 8; ++k) { v[k] = t[cg * 8 + k][px]; bv[k] = f2b(v[k]); }
    int ci = ci0 + cg * 8;
    *(u16x8*)(xpu + pixbase * 128 + ci) = bv;
    int pl = ci >> 6, cl = ci & 63;
    int kg = (cl >> 3) & 3, c = cl >> 5;
    int pk0 = __builtin_amdgcn_cvt_pk_fp8_f32(v[0], v[1], 0, false);
    pk0 = __builtin_amdgcn_cvt_pk_fp8_f32(v[2], v[3], pk0, true);
    int pk1 = __builtin_amdgcn_cvt_pk_fp8_f32(v[4], v[5], 0, false);
    pk1 = __builtin_amdgcn_cvt_pk_fp8_f32(v[6], v[7], pk1, true);
    i32x2 pk = {pk0, pk1};
    *(i32x2*)(xp8 + (size_t)pl * PLANE8 + pixbase * 64 + kg * 16 + c * 8) = pk;
  }
}

// ---- post weights [co][ci][3][3] f32 -> [cc][tap][co][32ci] bf16 ----------
__global__ void k_build_w(const float* __restrict__ src, __hip_bfloat16* __restrict__ dst) {
  int o = blockIdx.x * 256 + threadIdx.x;
  if (o >= 147456) return;
  int cl = o & 31, co = (o >> 5) & 127;
  int r9 = o >> 12;  // 0..35
  int tp = r9 % 9, cc = r9 / 9;
  int ci = cc * 32 + cl;
  ((unsigned short*)dst)[o] = f2b(src[((size_t)co * 128 + ci) * 9 + tp]);
}

// ---- expert weights -> [e][cc2][tap][co][64B dual-K perm] fp8 --------------
__global__ void k_build_w8(const float* __restrict__ src, unsigned char* __restrict__ dst) {
  int o = blockIdx.x * 256 + threadIdx.x;
  if (o >= 1179648) return;
  int e = o / 147456;
  int r = o - e * 147456;
  int cc2 = r / 73728;
  int r2 = r - cc2 * 73728;
  int tp = r2 >> 13;
  int r3 = r2 & 8191;
  int co = r3 >> 6, p = r3 & 63;
  int kg = p >> 4, c = (p >> 3) & 1, j = p & 7;
  int ci = cc2 * 64 + c * 32 + kg * 8 + j;
  dst[o] = f2fp8(src[(((size_t)e * 128 + co) * 128 + ci) * 9 + tp]);
}

// ---- expert conv3x3 fp8, G experts fused: 256px(2 rows) x 128co per block --
// R9 structure + setprio. 6 dbuf units (cc2,ky) of 45056 B. XCD k == image k.
template <int G>
__global__ __launch_bounds__(512, 2) void k_conv8(
    const unsigned char* __restrict__ xp8, const unsigned char* __restrict__ wt8,
    unsigned char* __restrict__ out8base, float* __restrict__ partials) {
  __shared__ __align__(16) char smem[90112];  // 2 x 45056
  const int cpx = (G * 512) >> 3;
  const int nid = (blockIdx.x & 7) * cpx + (blockIdx.x >> 3);
  const int eg = nid & (G - 1);
  const int t0 = nid / G;
  const int b = t0 >> 6, rp = t0 & 63, h0 = rp * 2;
  const unsigned char* wt = wt8 + (size_t)eg * 147456;
  unsigned char* out8 = out8base + (size_t)eg * 16777216ull;

  const int tid = threadIdx.x;
  const int lane = tid & 63, wid = tid >> 6;
  const int wm = wid >> 1, wn = wid & 1;
  const int rl = lane & 15, kg = lane >> 4;
  const int rowA = wm >> 1;
  const int colA = (wm & 1) * 64;

  int aoff[3][4], boff[3][4];
#pragma unroll
  for (int mb = 0; mb < 4; ++mb) {
    int col = colA + mb * 16 + rl;
#pragma unroll
    for (int kx = 0; kx < 3; ++kx) {
      int px = col + kx;
      aoff[kx][mb] = (rowA * 160 + px) * 64 + (kg ^ ((px >> 1) & 3)) * 16;
    }
  }
#pragma unroll
  for (int kx = 0; kx < 3; ++kx)
#pragma unroll
    for (int nb = 0; nb < 4; ++nb) {
      int co = wn * 64 + nb * 16 + rl;
      boff[kx][nb] = 20480 + ((kx * 128 + co) * 4 + (kg ^ ((co >> 1) & 3))) * 16;
    }

  // precomputed per-thread staging offsets (unit-invariant); LDS linear s*16
  int soff[6];
  bool isA[6];
#pragma unroll
  for (int it = 0; it < 6; ++it) {
    int s = it * 512 + tid;
    if (s < 1280) {
      int rw = (s >= 640) ? 1 : 0;
      int off = s - rw * 640;
      int px = off >> 2, q = off & 3;
      int qg = q ^ ((px >> 1) & 3);
      isA[it] = true;
      soff[it] = rw * 8320 + px * 64 + qg * 16;
    } else {
      int s2 = s - 1280;
      int tap = s2 >> 9, r3 = s2 & 511;
      int co = r3 >> 2, q = r3 & 3;
      int qg = q ^ ((co >> 1) & 3);
      isA[it] = false;
      soff[it] = tap * 8192 + co * 64 + qg * 16;
    }
  }

  f32x4 acc[4][4] = {};

#define STG8(bi, u)                                                            \
  {                                                                            \
    const int cc2_ = (u) / 3, ky_ = (u) % 3;                                   \
    char* D = smem + (bi) * 45056;                                             \
    const unsigned char* abase =                                               \
        xp8 + (size_t)cc2_ * PLANE8 + (size_t)(b * 130 + h0 + ky_) * 8320;     \
    const unsigned char* bbase = wt + cc2_ * 73728 + ky_ * 24576;              \
    _Pragma("unroll")                                                          \
    for (int it = 0; it < 5; ++it)                                             \
      gll16((isA[it] ? abase : bbase) + soff[it], D + (it * 512 + tid) * 16);  \
    if (tid < 256) gll16(bbase + soff[5], D + (5 * 512 + tid) * 16);           \
  }

  STG8(0, 0);
  for (int u = 0; u < 6; ++u) {
    const int cur = u & 1;
    __syncthreads();
    if (u + 1 < 6) STG8(cur ^ 1, u + 1);
    const char* Al = smem + cur * 45056;
    __builtin_amdgcn_s_setprio(1);
#pragma unroll
    for (int kx = 0; kx < 3; ++kx) {
      lx2 av[4], bv[4];
#pragma unroll
      for (int mb = 0; mb < 4; ++mb) av[mb] = *(const lx2*)(Al + aoff[kx][mb]);
#pragma unroll
      for (int nb = 0; nb < 4; ++nb) bv[nb] = *(const lx2*)(Al + boff[kx][nb]);
#pragma unroll
      for (int c = 0; c < 2; ++c)
#pragma unroll
        for (int mb = 0; mb < 4; ++mb)
#pragma unroll
          for (int nb = 0; nb < 4; ++nb)
            acc[mb][nb] = __builtin_amdgcn_mfma_f32_16x16x32_fp8_fp8(
                bv[nb][c], av[mb][c], acc[mb][nb], 0, 0, 0);
    }
    __builtin_amdgcn_s_setprio(0);
  }
#undef STG8

  // epilogue: fp8 pack + 4B stores, per-block GN partials
  float sv[4] = {0, 0, 0, 0}, qv[4] = {0, 0, 0, 0};
#pragma unroll
  for (int mb = 0; mb < 4; ++mb) {
    int px = colA + mb * 16 + rl;
    int h = h0 + rowA, w = px;
    size_t base = (((size_t)b * 128 + h) * 128 + w) * 128;
#pragma unroll
    for (int nb = 0; nb < 4; ++nb) {
      int co0 = wn * 64 + nb * 16 + kg * 4;
      f32x4 v = acc[mb][nb];
#pragma unroll
      for (int j = 0; j < 4; ++j) { sv[nb] += v[j]; qv[nb] += v[j] * v[j]; }
      int pk = __builtin_amdgcn_cvt_pk_fp8_f32(v[0], v[1], 0, false);
      pk = __builtin_amdgcn_cvt_pk_fp8_f32(v[2], v[3], pk, true);
      *(int*)(out8 + base + co0) = pk;
    }
  }
  __syncthreads();
  float* sg = (float*)smem;
  if (tid < 16) sg[tid] = 0.f;
  __syncthreads();
#pragma unroll
  for (int nb = 0; nb < 4; ++nb) {
    float a = sv[nb], q = qv[nb];
#pragma unroll
    for (int o = 32; o > 0; o >>= 1) { a += __shfl_down(a, o); q += __shfl_down(q, o); }
    if (lane == 0) {
      int g = wn * 4 + nb;
      atomicAdd(&sg[g * 2 + 0], a);
      atomicAdd(&sg[g * 2 + 1], q);
    }
  }
  __syncthreads();
  if (tid < 16)
    partials[((size_t)(eg * 8 + b) * 64 + rp) * 16 + tid] = sg[tid];
}

// ---- post conv3x3 bf16: same skeleton (2-row, 8 waves, 12 units of 45KB) ---
__global__ __launch_bounds__(512, 2) void k_conv(
    const unsigned short* __restrict__ xpu, const unsigned short* __restrict__ wtu,
    unsigned short* __restrict__ outu, float* __restrict__ partials) {
  __shared__ __align__(16) char smem[90112];  // 2 x 45056
  const int nid = (blockIdx.x & 7) * 64 + (blockIdx.x >> 3);
  const int b = nid >> 6, rp = nid & 63, h0 = rp * 2;
  const int tid = threadIdx.x;
  const int lane = tid & 63, wid = tid >> 6;
  const int wm = wid >> 1, wn = wid & 1;
  const int rl = lane & 15, kg = lane >> 4;
  const int rowA = wm >> 1;
  const int colA = (wm & 1) * 64;

  int aoff[3][4], boff[3][4];
#pragma unroll
  for (int mb = 0; mb < 4; ++mb) {
    int col = colA + mb * 16 + rl;
#pragma unroll
    for (int kx = 0; kx < 3; ++kx) {
      int px = col + kx;
      aoff[kx][mb] = (rowA * 160 + px) * 64 + (kg ^ ((px >> 1) & 3)) * 16;
    }
  }
#pragma unroll
  for (int kx = 0; kx < 3; ++kx)
#pragma unroll
    for (int nb = 0; nb < 4; ++nb) {
      int co = wn * 64 + nb * 16 + rl;
      boff[kx][nb] = 20480 + ((kx * 128 + co) * 4 + (kg ^ ((co >> 1) & 3))) * 16;
    }

  // per-thread staging offsets; A: 2 rows x 160px x 64B (bf16 32ci slice),
  // row byte-stride 33280, px byte-stride 256. B: 3 taps x 128co x 64B.
  int soff[6];
  bool isA[6];
#pragma unroll
  for (int it = 0; it < 6; ++it) {
    int s = it * 512 + tid;
    if (s < 1280) {
      int rw = (s >= 640) ? 1 : 0;
      int off = s - rw * 640;
      int px = off >> 2, q = off & 3;
      int qg = q ^ ((px >> 1) & 3);
      isA[it] = true;
      soff[it] = rw * 33280 + px * 256 + qg * 16;
    } else {
      int s2 = s - 1280;
      int tap = s2 >> 9, r3 = s2 & 511;
      int co = r3 >> 2, q = r3 & 3;
      int qg = q ^ ((co >> 1) & 3);
      isA[it] = false;
      soff[it] = tap * 8192 + co * 64 + qg * 16;
    }
  }

  f32x4 acc[4][4] = {};
  const char* xpb = (const char*)xpu;
  const char* wtb = (const char*)wtu;

#define STAGE(bi, u)                                                           \
  {                                                                            \
    const int cc_ = (u) / 3, ky_ = (u) % 3;                                    \
    char* D = smem + (bi) * 45056;                                             \
    const char* abase =                                                        \
        xpb + (size_t)(b * 130 + h0 + ky_) * 33280 + cc_ * 64;                 \
    const char* bbase = wtb + cc_ * 73728 + ky_ * 24576;                       \
    _Pragma("unroll")                                                          \
    for (int it = 0; it < 5; ++it)                                             \
      gll16((isA[it] ? abase : bbase) + soff[it], D + (it * 512 + tid) * 16);  \
    if (tid < 256) gll16(bbase + soff[5], D + (5 * 512 + tid) * 16);           \
  }

  STAGE(0, 0);
  for (int u = 0; u < 12; ++u) {
    const int cur = u & 1;
    __syncthreads();
    if (u + 1 < 12) STAGE(cur ^ 1, u + 1);
    const char* Al = smem + cur * 45056;
    __builtin_amdgcn_s_setprio(1);
#pragma unroll
    for (int kx = 0; kx < 3; ++kx) {
      bf16x8 aF[4], bF[4];
#pragma unroll
      for (int mb = 0; mb < 4; ++mb) aF[mb] = *(const bf16x8*)(Al + aoff[kx][mb]);
#pragma unroll
      for (int nb = 0; nb < 4; ++nb) bF[nb] = *(const bf16x8*)(Al + boff[kx][nb]);
#pragma unroll
      for (int mb = 0; mb < 4; ++mb)
#pragma unroll
        for (int nb = 0; nb < 4; ++nb)
          acc[mb][nb] = __builtin_amdgcn_mfma_f32_16x16x32_bf16(
              bF[nb], aF[mb], acc[mb][nb], 0, 0, 0);
    }
    __builtin_amdgcn_s_setprio(0);
  }
#undef STAGE

  float sv[4] = {0, 0, 0, 0}, qv[4] = {0, 0, 0, 0};
#pragma unroll
  for (int mb = 0; mb < 4; ++mb) {
    int px = colA + mb * 16 + rl;
    int h = h0 + rowA;
    size_t base = (((size_t)b * 128 + h) * 128 + px) * 128;
#pragma unroll
    for (int nb = 0; nb < 4; ++nb) {
      int co0 = wn * 64 + nb * 16 + kg * 4;
      u16x4 pk;
#pragma unroll
      for (int j = 0; j < 4; ++j) {
        float v = acc[mb][nb][j];
        pk[j] = f2b(v);
        sv[nb] += v; qv[nb] += v * v;
      }
      *(u16x4*)(outu + base + co0) = pk;
    }
  }
  __syncthreads();
  float* sg = (float*)smem;
  if (tid < 16) sg[tid] = 0.f;
  __syncthreads();
#pragma unroll
  for (int nb = 0; nb < 4; ++nb) {
    float a = sv[nb], q = qv[nb];
#pragma unroll
    for (int o = 32; o > 0; o >>= 1) { a += __shfl_down(a, o); q += __shfl_down(q, o); }
    if (lane == 0) {
      int g = wn * 4 + nb;
      atomicAdd(&sg[g * 2 + 0], a);
      atomicAdd(&sg[g * 2 + 1], q);
    }
  }
  __syncthreads();
  if (tid < 16) partials[(size_t)nid * 16 + tid] = sg[tid];
}

// ---- reduce per-block partials [set][b][nper][16] -> stats[set][128] ------
__global__ void k_redstats(const float* __restrict__ partials, float* __restrict__ stats,
                           int nper) {
  int set = blockIdx.x;
  const float* p = partials + (size_t)set * 8 * nper * 16;
  float* st = stats + set * 128;
  int t = threadIdx.x;
  int o = t >> 2, j = t & 3;
  int b = o >> 4, slot = o & 15;
  int chunk = nper >> 2;
  float s = 0.f;
  for (int i = j * chunk; i < (j + 1) * chunk; ++i)
    s += p[((size_t)b * nper + i) * 16 + slot];
  s += __shfl_xor(s, 1);
  s += __shfl_xor(s, 2);
  if (j == 0) st[o] = s;
}

// ---- reduce merge partials (8192 x 16) -> stats2 --------------------------
__global__ void k_redstats2(const float* __restrict__ p2, float* __restrict__ st) {
  int o = blockIdx.x;
  int b = o >> 4, slot = o & 15;
  float s = 0.f;
  for (int i = threadIdx.x; i < 1024; i += 256)
    s += p2[((size_t)b * 1024 + i) * 16 + slot];
#pragma unroll
  for (int off = 32; off > 0; off >>= 1) s += __shfl_down(s, off);
  __shared__ float wsm[4];
  int lane = threadIdx.x & 63, wv = threadIdx.x >> 6;
  if (lane == 0) wsm[wv] = s;
  __syncthreads();
  if (threadIdx.x == 0) st[o] = wsm[0] + wsm[1] + wsm[2] + wsm[3];
}

// ---- merge NEXP fp8 experts ------------------------------------------------
template <int NEXP>
__global__ void k_merge(const unsigned char* __restrict__ c0,
                        const unsigned char* __restrict__ c1,
                        const unsigned char* __restrict__ c2,
                        const unsigned char* __restrict__ c3,
                        const float* __restrict__ st, const float* __restrict__ eg,
                        const float* __restrict__ eb, const float* __restrict__ wts,
                        unsigned short* __restrict__ merged,
                        const unsigned short* __restrict__ xp,
                        float* __restrict__ partials2, int e0, int flags) {
  __shared__ float sg[16];
  int tid = threadIdx.x;
  if (tid < 16) sg[tid] = 0.f;
  __syncthreads();
  size_t idx = ((size_t)blockIdx.x * 256 + tid) * 8;
  int co0 = (int)(idx & 127);
  size_t pix = idx >> 7;
  int w = (int)(pix & 127), h = (int)((pix >> 7) & 127), b = (int)(pix >> 14);
  int g = co0 >> 4;
  const float cnt = 16.f * 128.f * 128.f;
  int patch = (h >> 4) * 8 + (w >> 4);
  const unsigned char* cs[4] = {c0, c1, c2, c3};
  float a[8] = {0, 0, 0, 0, 0, 0, 0, 0};
#pragma unroll
  for (int k = 0; k < NEXP; ++k) {
    int e = e0 + k;
    float mean = st[e * 128 + (b * 8 + g) * 2] / cnt;
    float var = st[e * 128 + (b * 8 + g) * 2 + 1] / cnt - mean * mean;
    float rstd = rsqrtf(var + 1e-5f);
    float we = wts[patch * 8 + e];
    f32x4 g0 = *(const f32x4*)(eg + e * 128 + co0);
    f32x4 g1 = *(const f32x4*)(eg + e * 128 + co0 + 4);
    f32x4 b0 = *(const f32x4*)(eb + e * 128 + co0);
    f32x4 b1 = *(const f32x4*)(eb + e * 128 + co0 + 4);
    u32x2 cv = *(const u32x2*)(cs[k] + idx);
    f32x2 d0 = __builtin_amdgcn_cvt_pk_f32_fp8(cv[0], false);
    f32x2 d1 = __builtin_amdgcn_cvt_pk_f32_fp8(cv[0], true);
    f32x2 d2 = __builtin_amdgcn_cvt_pk_f32_fp8(cv[1], false);
    f32x2 d3 = __builtin_amdgcn_cvt_pk_f32_fp8(cv[1], true);
    float d[8] = {d0[0], d0[1], d1[0], d1[1], d2[0], d2[1], d3[0], d3[1]};
#pragma unroll
    for (int i = 0; i < 8; ++i) {
      float gi = (i < 4) ? g0[i] : g1[i - 4];
      float bi = (i < 4) ? b0[i] : b1[i - 4];
      float A = rstd * gi;
      float B = bi - mean * A;
      a[i] += we * fsilu(d[i] * A + B);
    }
  }
  if (flags & 1) {
    u16x8 mv = *(const u16x8*)(merged + idx);
#pragma unroll
    for (int i = 0; i < 8; ++i) a[i] += b2f(mv[i]);
  }
  u16x8 out;
  float s = 0.f, q = 0.f;
  if (flags & 2) {
    const unsigned short* xr =
        xp + (((size_t)b * 130 + h + 1) * 130 + (w + 1)) * 128 + co0;
    u16x8 xv = *(const u16x8*)xr;
#pragma unroll
    for (int i = 0; i < 8; ++i) {
      a[i] += b2f(xv[i]);
      out[i] = f2b(a[i]);
      float rv = b2f(out[i]);
      s += rv; q += rv * rv;
    }
  } else {
#pragma unroll
    for (int i = 0; i < 8; ++i) out[i] = f2b(a[i]);
  }
  *(u16x8*)(merged + idx) = out;
  if (flags & 2) {
    atomicAdd(&sg[g * 2 + 0], s);
    atomicAdd(&sg[g * 2 + 1], q);
    __syncthreads();
    if (tid < 16) partials2[(size_t)blockIdx.x * 16 + tid] = sg[tid];
  }
}

// ---- y = x + gamma*silu(gn(M)); bf16, in place into xpad -------------------
__global__ void k_ypass(const unsigned short* __restrict__ merged,
                        unsigned short* __restrict__ xp,
                        const float* __restrict__ st, const float* __restrict__ mg,
                        const float* __restrict__ mbv, const float* __restrict__ gptr) {
  size_t idx = ((size_t)blockIdx.x * 256 + threadIdx.x) * 8;
  int co0 = (int)(idx & 127);
  size_t pix = idx >> 7;
  int w = (int)(pix & 127), h = (int)((pix >> 7) & 127), b = (int)(pix >> 14);
  int g = co0 >> 4;
  const float cnt = 16.f * 128.f * 128.f;
  float mean = st[(b * 8 + g) * 2] / cnt;
  float var = st[(b * 8 + g) * 2 + 1] / cnt - mean * mean;
  float rstd = rsqrtf(var + 1e-5f);
  float gm = gptr[0];
  unsigned short* xr = xp + (((size_t)b * 130 + h + 1) * 130 + (w + 1)) * 128 + co0;
  u16x8 xv = *(const u16x8*)xr;
  u16x8 mv = *(const u16x8*)(merged + idx);
  u16x8 yv;
#pragma unroll
  for (int i = 0; i < 8; ++i) {
    float xf = b2f(xv[i]);
    float M = b2f(mv[i]);
    float xn = (M - mean) * rstd * mg[co0 + i] + mbv[co0 + i];
    yv[i] = f2b(xf + gm * fsilu(xn));
  }
  *(u16x8*)xr = yv;
}

// ---- final: out = silu(gn3(conv3)), NHWC bf16 -> NCHW f32 ------------------
__global__ void k_final(const __hip_bfloat16* __restrict__ conv, const float* __restrict__ st,
                        const float* __restrict__ pg, const float* __restrict__ pb,
                        float* __restrict__ out) {
  int bx = blockIdx.x;
  int wb = bx & 1, h = (bx >> 1) & 127, b = bx >> 8;
  int w0 = wb * 64;
  __shared__ float t[64][129];
  int tid = threadIdx.x;
  const float cnt = 16.f * 128.f * 128.f;
  const unsigned short* cu = (const unsigned short*)conv;
#pragma unroll
  for (int r = 0; r < 32; ++r) {
    int e2 = r * 256 + tid;
    int co = e2 & 127, wl = e2 >> 7;
    int g = co >> 4;
    float mean = st[(b * 8 + g) * 2] / cnt;
    float var = st[(b * 8 + g) * 2 + 1] / cnt - mean * mean;
    float rstd = rsqrtf(var + 1e-5f);
    float v = b2f(cu[(((size_t)b * 128 + h) * 128 + w0 + wl) * 128 + co]);
    float xn = (v - mean) * rstd * pg[co] + pb[co];
    t[wl][co] = fsilu(xn);
  }
  __syncthreads();
#pragma unroll
  for (int r = 0; r < 8; ++r) {
    int f = r * 256 + tid;
    int jb = f & 15, co = f >> 4;
    f32x4 o;
#pragma unroll
    for (int j = 0; j < 4; ++j) o[j] = t[jb * 4 + j][co];
    *(f32x4*)&out[(((size_t)b * 128 + co) * 128 + h) * 128 + w0 + jb * 4] = o;
  }
}

// ---------------------------------------------------------------------------
extern "C" void kernel_launch(void* const* d_in, const int* in_sizes, int n_in,
                              void* d_out, int out_size, void* d_ws, size_t ws_size,
                              hipStream_t stream) {
  const float* x        = (const float*)d_in[0];
  const float* expert_w = (const float*)d_in[1];
  const float* expert_g = (const float*)d_in[2];
  const float* expert_b = (const float*)d_in[3];
  const float* router_w = (const float*)d_in[4];
  const float* router_b = (const float*)d_in[5];
  const float* merge_g  = (const float*)d_in[6];
  const float* merge_b  = (const float*)d_in[7];
  const float* gamma    = (const float*)d_in[8];
  const float* post_w   = (const float*)d_in[9];
  const float* post_g   = (const float*)d_in[10];
  const float* post_b   = (const float*)d_in[11];

  char* ws = (char*)d_ws;
  float* wts            = (float*)(ws + 0);                  // 2048
  float* stats          = (float*)(ws + 2048);               // 5120
  float* partials       = (float*)(ws + 8192);               // 262144
  float* partials2      = (float*)(ws + 270336);             // 524288
  unsigned short* wtbp  = (unsigned short*)(ws + 794624);    // 294912
  unsigned char* wtb8   = (unsigned char*)(ws + 1089536);    // 1179648
  unsigned short* xpad  = (unsigned short*)(ws + 2269184);   // 34611200 (+8192 slack)
  unsigned char* xpad8  = (unsigned char*)(ws + 36888576);   // 17305600 (+4096 slack)
  const size_t BUFS = 54198272ull;
  const size_t FB = 16777216ull;
  const size_t NEED2 = BUFS + 2 * FB + 33554432ull;
  const size_t NEED4 = BUFS + 4 * FB + 33554432ull;
  int nbuf = (ws_size >= NEED4) ? 4 : 2;
  unsigned char* bufs0 = (unsigned char*)(ws + BUFS);
  unsigned short* merged = (unsigned short*)(ws + BUFS + (size_t)nbuf * FB);
  unsigned short* pbuf = (unsigned short*)(ws + BUFS);  // post conv out (reuse)
  if (ws_size < NEED2) {
    hipMemsetAsync(d_out, 0, (size_t)out_size * 4, stream);
    return;
  }

  k_zborder<<<17, 256, 0, stream>>>(xpad, xpad8);
  k_router<<<1, 64, 0, stream>>>(router_w, router_b, wts);
  k_build_xpad<<<4096, 256, 0, stream>>>(x, (__hip_bfloat16*)xpad, xpad8);
  k_build_w<<<576, 256, 0, stream>>>(post_w, (__hip_bfloat16*)wtbp);
  k_build_w8<<<4608, 256, 0, stream>>>(expert_w, wtb8);

  if (nbuf == 4) {
    for (int p = 0; p < 2; ++p) {
      k_conv8<4><<<2048, 512, 0, stream>>>(xpad8, wtb8 + (size_t)(p * 4) * 147456,
                                           bufs0, partials);
      k_redstats<<<4, 512, 0, stream>>>(partials, stats + p * 4 * 128, 64);
      int flags = (p > 0 ? 1 : 0) | (p == 1 ? 2 : 0);
      k_merge<4><<<8192, 256, 0, stream>>>(bufs0, bufs0 + FB, bufs0 + 2 * FB,
                                           bufs0 + 3 * FB, stats, expert_g, expert_b,
                                           wts, merged, xpad, partials2, p * 4, flags);
    }
  } else {
    for (int p = 0; p < 4; ++p) {
      k_conv8<2><<<1024, 512, 0, stream>>>(xpad8, wtb8 + (size_t)(p * 2) * 147456,
                                           bufs0, partials);
      k_redstats<<<2, 512, 0, stream>>>(partials, stats + p * 2 * 128, 64);
      int flags = (p > 0 ? 1 : 0) | (p == 3 ? 2 : 0);
      k_merge<2><<<8192, 256, 0, stream>>>(bufs0, bufs0 + FB, bufs0, bufs0 + FB,
                                           stats, expert_g, expert_b, wts, merged,
                                           xpad, partials2, p * 2, flags);
    }
  }
  k_redstats2<<<128, 256, 0, stream>>>(partials2, stats + 8 * 128);
  k_ypass<<<8192, 256, 0, stream>>>(merged, xpad, stats + 8 * 128, merge_g, merge_b, gamma);
  k_conv<<<512, 512, 0, stream>>>(xpad, wtbp, pbuf, partials);
  k_redstats<<<1, 512, 0, stream>>>(partials, stats + 9 * 128, 64);
  k_final<<<2048, 256, 0, stream>>>((const __hip_bfloat16*)pbuf, stats + 9 * 128,
                                    post_g, post_b, (float*)d_out);
}

// Round 12
// 447.378 us; speedup vs baseline: 1.0323x; 1.0021x over previous
//
#include <hip/hip_runtime.h>
#include <hip/hip_bf16.h>

// ---------------------------------------------------------------------------
// PCELayer. Expert convs: fp8 implicit GEMM, 2-row 256px x 128co blocks,
// 8 waves. R12: T3+T4 counted-vmcnt pipeline -- 3 LDS buffers, depth-2
// prefetch, s_waitcnt vmcnt(6) + raw s_barrier (never drain to 0 in loop),
// uniform 6 gll16/thread/unit. Post conv: same treatment (12 units).
// No setprio (R11 measured -5%).
// ---------------------------------------------------------------------------

typedef __attribute__((ext_vector_type(8))) short bf16x8;
typedef __attribute__((ext_vector_type(4))) float f32x4;
typedef __attribute__((ext_vector_type(2))) float f32x2;
typedef __attribute__((ext_vector_type(8))) unsigned short u16x8;
typedef __attribute__((ext_vector_type(4))) unsigned short u16x4;
typedef __attribute__((ext_vector_type(2))) unsigned int u32x2;
typedef __attribute__((ext_vector_type(2))) int i32x2;
typedef __attribute__((ext_vector_type(2))) long lx2;

__device__ __forceinline__ float b2f(unsigned short u) {
  unsigned int v = ((unsigned int)u) << 16;
  return __builtin_bit_cast(float, v);
}
__device__ __forceinline__ unsigned short f2b(float f) {
  __hip_bfloat16 h = __float2bfloat16(f);
  return __builtin_bit_cast(unsigned short, h);
}
__device__ __forceinline__ float fsilu(float x) {
  float e = __expf(-x);
  return x * __builtin_amdgcn_rcpf(1.f + e);
}
__device__ __forceinline__ void gll16(const void* g, void* l) {
  __builtin_amdgcn_global_load_lds(
      (const __attribute__((address_space(1))) unsigned int*)g,
      (__attribute__((address_space(3))) unsigned int*)l, 16, 0, 0);
}
__device__ __forceinline__ unsigned char f2fp8(float v) {
  return (unsigned char)(__builtin_amdgcn_cvt_pk_fp8_f32(v, v, 0, false) & 0xff);
}

#define PLANE8 8652800ull  // 8*130*130*64 bytes per 64-ci fp8 plane (2 planes)

// ---- router ---------------------------------------------------------------
__global__ void k_router(const float* __restrict__ rw, const float* __restrict__ rb,
                         float* __restrict__ wts) {
  int t = threadIdx.x;
  if (t >= 64) return;
  int py = t >> 3, px = t & 7;
  float cy = (py + 0.5f) / 8.f, cx = (px + 0.5f) / 8.f;
  const float PI = 3.14159265358979323846f;
  float f[16];
#pragma unroll
  for (int k = 0; k < 4; ++k) {
    float fr = (float)(1 << k) * PI;
    f[k] = sinf(cy * fr); f[4 + k] = cosf(cy * fr);
    f[8 + k] = sinf(cx * fr); f[12 + k] = cosf(cx * fr);
  }
  float lg[8], mx = -1e30f;
#pragma unroll
  for (int e = 0; e < 8; ++e) {
    float a = rb[e];
#pragma unroll
    for (int k = 0; k < 16; ++k) a += f[k] * rw[k * 8 + e];
    lg[e] = a; mx = fmaxf(mx, a);
  }
  float s = 0.f;
#pragma unroll
  for (int e = 0; e < 8; ++e) { lg[e] = __expf(lg[e] - mx); s += lg[e]; }
  float inv = 1.f / s;
#pragma unroll
  for (int e = 0; e < 8; ++e) wts[t * 8 + e] = lg[e] * inv;
}

// ---- zero halo borders of xpad (bf16) and xpad8 (2 fp8 planes) -------------
__global__ void k_zborder(unsigned short* __restrict__ xpu,
                          unsigned char* __restrict__ xp8) {
  int idx = blockIdx.x * 256 + threadIdx.x;
  if (idx >= 8 * 516) return;
  int b = idx / 516, pxi = idx - b * 516;
  int r, c;
  if (pxi < 130)      { r = 0;   c = pxi; }
  else if (pxi < 260) { r = 129; c = pxi - 130; }
  else if (pxi < 388) { r = pxi - 260 + 1; c = 0; }
  else                { r = pxi - 388 + 1; c = 129; }
  size_t pix = (size_t)(b * 130 + r) * 130 + c;
  unsigned short* p = xpu + pix * 128;
#pragma unroll
  for (int j = 0; j < 16; ++j) *(u16x8*)(p + j * 8) = (u16x8)0;
#pragma unroll
  for (int cc = 0; cc < 2; ++cc) {
    f32x4* q = (f32x4*)(xp8 + cc * PLANE8 + pix * 64);
#pragma unroll
    for (int j = 0; j < 4; ++j) q[j] = (f32x4)0.f;
  }
}

// ---- x (NCHW f32) -> xpad bf16 [pix][128] + xpad8 fp8 dual-K perm planes ---
__global__ void k_build_xpad(const float* __restrict__ x, __hip_bfloat16* __restrict__ xp,
                             unsigned char* __restrict__ xp8) {
  int bx = blockIdx.x;
  int wb = bx & 1, cib = (bx >> 1) & 1;
  int h = (bx >> 2) & 127, b = bx >> 9;
  int w0 = wb * 64, ci0 = cib * 64;
  __shared__ float t[64][65];
  int tid = threadIdx.x;
#pragma unroll
  for (int r = 0; r < 16; ++r) {
    int idx = r * 256 + tid;
    int i = idx >> 6, j = idx & 63;  // i: ci, j: w
    t[i][j] = x[(((size_t)b * 128 + ci0 + i) * 128 + h) * 128 + w0 + j];
  }
  __syncthreads();
  unsigned short* xpu = (unsigned short*)xp;
#pragma unroll
  for (int r = 0; r < 2; ++r) {
    int s = r * 256 + tid;          // 512 slots: 64 px x 8 ci-groups
    int px = s >> 3, cg = s & 7;
    size_t pixbase = ((size_t)b * 130 + h + 1) * 130 + (w0 + px + 1);
    float v[8];
    u16x8 bv;
#pragma unroll
    for (int k = 0; k < 8; ++k) { v[k] = t[cg * 8 + k][px]; bv[k] = f2b(v[k]); }
    int ci = ci0 + cg * 8;
    *(u16x8*)(xpu + pixbase * 128 + ci) = bv;
    int pl = ci >> 6, cl = ci & 63;
    int kg = (cl >> 3) & 3, c = cl >> 5;
    int pk0 = __builtin_amdgcn_cvt_pk_fp8_f32(v[0], v[1], 0, false);
    pk0 = __builtin_amdgcn_cvt_pk_fp8_f32(v[2], v[3], pk0, true);
    int pk1 = __builtin_amdgcn_cvt_pk_fp8_f32(v[4], v[5], 0, false);
    pk1 = __builtin_amdgcn_cvt_pk_fp8_f32(v[6], v[7], pk1, true);
    i32x2 pk = {pk0, pk1};
    *(i32x2*)(xp8 + (size_t)pl * PLANE8 + pixbase * 64 + kg * 16 + c * 8) = pk;
  }
}

// ---- post weights [co][ci][3][3] f32 -> [cc][tap][co][32ci] bf16 ----------
__global__ void k_build_w(const float* __restrict__ src, __hip_bfloat16* __restrict__ dst) {
  int o = blockIdx.x * 256 + threadIdx.x;
  if (o >= 147456) return;
  int cl = o & 31, co = (o >> 5) & 127;
  int r9 = o >> 12;  // 0..35
  int tp = r9 % 9, cc = r9 / 9;
  int ci = cc * 32 + cl;
  ((unsigned short*)dst)[o] = f2b(src[((size_t)co * 128 + ci) * 9 + tp]);
}

// ---- expert weights -> [e][cc2][tap][co][64B dual-K perm] fp8 --------------
__global__ void k_build_w8(const float* __restrict__ src, unsigned char* __restrict__ dst) {
  int o = blockIdx.x * 256 + threadIdx.x;
  if (o >= 1179648) return;
  int e = o / 147456;
  int r = o - e * 147456;
  int cc2 = r / 73728;
  int r2 = r - cc2 * 73728;
  int tp = r2 >> 13;
  int r3 = r2 & 8191;
  int co = r3 >> 6, p = r3 & 63;
  int kg = p >> 4, c = (p >> 3) & 1, j = p & 7;
  int ci = cc2 * 64 + c * 32 + kg * 8 + j;
  dst[o] = f2fp8(src[(((size_t)e * 128 + co) * 128 + ci) * 9 + tp]);
}

// ---- expert conv3x3 fp8, G experts fused: 256px(2 rows) x 128co per block --
// 6 units (cc2,ky), 3 LDS buffers, counted-vmcnt depth-2 pipeline.
template <int G>
__global__ __launch_bounds__(512, 2) void k_conv8(
    const unsigned char* __restrict__ xp8, const unsigned char* __restrict__ wt8,
    unsigned char* __restrict__ out8base, float* __restrict__ partials) {
  __shared__ __align__(16) char smem[147456];  // 3 x 49152 (45056 + dummy tail)
  const int cpx = (G * 512) >> 3;
  const int nid = (blockIdx.x & 7) * cpx + (blockIdx.x >> 3);
  const int eg = nid & (G - 1);
  const int t0 = nid / G;
  const int b = t0 >> 6, rp = t0 & 63, h0 = rp * 2;
  const unsigned char* wt = wt8 + (size_t)eg * 147456;
  unsigned char* out8 = out8base + (size_t)eg * 16777216ull;

  const int tid = threadIdx.x;
  const int lane = tid & 63, wid = tid >> 6;
  const int wm = wid >> 1, wn = wid & 1;
  const int rl = lane & 15, kg = lane >> 4;
  const int rowA = wm >> 1;
  const int colA = (wm & 1) * 64;

  int aoff[3][4], boff[3][4];
#pragma unroll
  for (int mb = 0; mb < 4; ++mb) {
    int col = colA + mb * 16 + rl;
#pragma unroll
    for (int kx = 0; kx < 3; ++kx) {
      int px = col + kx;
      aoff[kx][mb] = (rowA * 160 + px) * 64 + (kg ^ ((px >> 1) & 3)) * 16;
    }
  }
#pragma unroll
  for (int kx = 0; kx < 3; ++kx)
#pragma unroll
    for (int nb = 0; nb < 4; ++nb) {
      int co = wn * 64 + nb * 16 + rl;
      boff[kx][nb] = 20480 + ((kx * 128 + co) * 4 + (kg ^ ((co >> 1) & 3))) * 16;
    }

  // uniform 6 staging loads/thread: slots 0..2815 real (A 0..1279, B 1280..2815),
  // slots 2816..3071 dummy (land in 45056..49151 tail, never read).
  int soff[6], loff[6];
  bool isA[6];
#pragma unroll
  for (int it = 0; it < 6; ++it) {
    int s = it * 512 + tid;
    int sc = (s < 2816) ? s : (s - 256);  // dummy threads mirror valid B slots
    if (sc < 1280) {
      int rw = (sc >= 640) ? 1 : 0;
      int off = sc - rw * 640;
      int px = off >> 2, q = off & 3;
      int qg = q ^ ((px >> 1) & 3);
      isA[it] = true;
      soff[it] = rw * 8320 + px * 64 + qg * 16;
    } else {
      int s2 = sc - 1280;
      int tap = s2 >> 9, r3 = s2 & 511;
      int co = r3 >> 2, q = r3 & 3;
      int qg = q ^ ((co >> 1) & 3);
      isA[it] = false;
      soff[it] = tap * 8192 + co * 64 + qg * 16;
    }
    loff[it] = s * 16;
  }

  f32x4 acc[4][4] = {};

#define STG8(bi, u)                                                            \
  {                                                                            \
    const int cc2_ = (u) / 3, ky_ = (u) % 3;                                   \
    char* D = smem + (bi) * 49152;                                             \
    const unsigned char* abase =                                               \
        xp8 + (size_t)cc2_ * PLANE8 + (size_t)(b * 130 + h0 + ky_) * 8320;     \
    const unsigned char* bbase = wt + cc2_ * 73728 + ky_ * 24576;              \
    _Pragma("unroll")                                                          \
    for (int it = 0; it < 6; ++it)                                             \
      gll16((isA[it] ? abase : bbase) + soff[it], D + loff[it]);               \
  }

  STG8(0, 0);
  STG8(1, 1);
#pragma unroll
  for (int u = 0; u < 6; ++u) {
    if (u < 5)
      asm volatile("s_waitcnt vmcnt(6)" ::: "memory");
    else
      asm volatile("s_waitcnt vmcnt(0)" ::: "memory");
    __builtin_amdgcn_s_barrier();
    if (u + 2 < 6) {
      STG8((u + 2) % 3, u + 2);  // loads fly across future barriers
    }
    const char* Al = smem + (u % 3) * 49152;
#pragma unroll
    for (int kx = 0; kx < 3; ++kx) {
      lx2 av[4], bv[4];
#pragma unroll
      for (int mb = 0; mb < 4; ++mb) av[mb] = *(const lx2*)(Al + aoff[kx][mb]);
#pragma unroll
      for (int nb = 0; nb < 4; ++nb) bv[nb] = *(const lx2*)(Al + boff[kx][nb]);
#pragma unroll
      for (int c = 0; c < 2; ++c)
#pragma unroll
        for (int mb = 0; mb < 4; ++mb)
#pragma unroll
          for (int nb = 0; nb < 4; ++nb)
            acc[mb][nb] = __builtin_amdgcn_mfma_f32_16x16x32_fp8_fp8(
                bv[nb][c], av[mb][c], acc[mb][nb], 0, 0, 0);
    }
  }
#undef STG8

  // epilogue: fp8 pack + 4B stores, per-block GN partials
  float sv[4] = {0, 0, 0, 0}, qv[4] = {0, 0, 0, 0};
#pragma unroll
  for (int mb = 0; mb < 4; ++mb) {
    int px = colA + mb * 16 + rl;
    int h = h0 + rowA, w = px;
    size_t base = (((size_t)b * 128 + h) * 128 + w) * 128;
#pragma unroll
    for (int nb = 0; nb < 4; ++nb) {
      int co0 = wn * 64 + nb * 16 + kg * 4;
      f32x4 v = acc[mb][nb];
#pragma unroll
      for (int j = 0; j < 4; ++j) { sv[nb] += v[j]; qv[nb] += v[j] * v[j]; }
      int pk = __builtin_amdgcn_cvt_pk_fp8_f32(v[0], v[1], 0, false);
      pk = __builtin_amdgcn_cvt_pk_fp8_f32(v[2], v[3], pk, true);
      *(int*)(out8 + base + co0) = pk;
    }
  }
  __syncthreads();
  float* sg = (float*)smem;
  if (tid < 16) sg[tid] = 0.f;
  __syncthreads();
#pragma unroll
  for (int nb = 0; nb < 4; ++nb) {
    float a = sv[nb], q = qv[nb];
#pragma unroll
    for (int o = 32; o > 0; o >>= 1) { a += __shfl_down(a, o); q += __shfl_down(q, o); }
    if (lane == 0) {
      int g = wn * 4 + nb;
      atomicAdd(&sg[g * 2 + 0], a);
      atomicAdd(&sg[g * 2 + 1], q);
    }
  }
  __syncthreads();
  if (tid < 16)
    partials[((size_t)(eg * 8 + b) * 64 + rp) * 16 + tid] = sg[tid];
}

// ---- post conv3x3 bf16: same skeleton, 12 units, counted-vmcnt pipeline ----
__global__ __launch_bounds__(512, 2) void k_conv(
    const unsigned short* __restrict__ xpu, const unsigned short* __restrict__ wtu,
    unsigned short* __restrict__ outu, float* __restrict__ partials) {
  __shared__ __align__(16) char smem[147456];  // 3 x 49152
  const int nid = (blockIdx.x & 7) * 64 + (blockIdx.x >> 3);
  const int b = nid >> 6, rp = nid & 63, h0 = rp * 2;
  const int tid = threadIdx.x;
  const int lane = tid & 63, wid = tid >> 6;
  const int wm = wid >> 1, wn = wid & 1;
  const int rl = lane & 15, kg = lane >> 4;
  const int rowA = wm >> 1;
  const int colA = (wm & 1) * 64;

  int aoff[3][4], boff[3][4];
#pragma unroll
  for (int mb = 0; mb < 4; ++mb) {
    int col = colA + mb * 16 + rl;
#pragma unroll
    for (int kx = 0; kx < 3; ++kx) {
      int px = col + kx;
      aoff[kx][mb] = (rowA * 160 + px) * 64 + (kg ^ ((px >> 1) & 3)) * 16;
    }
  }
#pragma unroll
  for (int kx = 0; kx < 3; ++kx)
#pragma unroll
    for (int nb = 0; nb < 4; ++nb) {
      int co = wn * 64 + nb * 16 + rl;
      boff[kx][nb] = 20480 + ((kx * 128 + co) * 4 + (kg ^ ((co >> 1) & 3))) * 16;
    }

  int soff[6], loff[6];
  bool isA[6];
#pragma unroll
  for (int it = 0; it < 6; ++it) {
    int s = it * 512 + tid;
    int sc = (s < 2816) ? s : (s - 256);
    if (sc < 1280) {
      int rw = (sc >= 640) ? 1 : 0;
      int off = sc - rw * 640;
      int px = off >> 2, q = off & 3;
      int qg = q ^ ((px >> 1) & 3);
      isA[it] = true;
      soff[it] = rw * 33280 + px * 256 + qg * 16;
    } else {
      int s2 = sc - 1280;
      int tap = s2 >> 9, r3 = s2 & 511;
      int co = r3 >> 2, q = r3 & 3;
      int qg = q ^ ((co >> 1) & 3);
      isA[it] = false;
      soff[it] = tap * 8192 + co * 64 + qg * 16;
    }
    loff[it] = s * 16;
  }

  f32x4 acc[4][4] = {};
  const char* xpb = (const char*)xpu;
  const char* wtb = (const char*)wtu;

#define STAGE(bi, u)                                                           \
  {                                                                            \
    const int cc_ = (u) / 3, ky_ = (u) % 3;                                    \
    char* D = smem + (bi) * 49152;                                             \
    const char* abase =                                                        \
        xpb + (size_t)(b * 130 + h0 + ky_) * 33280 + cc_ * 64;                 \
    const char* bbase = wtb + cc_ * 73728 + ky_ * 24576;                       \
    _Pragma("unroll")                                                          \
    for (int it = 0; it < 6; ++it)                                             \
      gll16((isA[it] ? abase : bbase) + soff[it], D + loff[it]);               \
  }

  STAGE(0, 0);
  STAGE(1, 1);
#pragma unroll
  for (int u = 0; u < 12; ++u) {
    if (u < 11)
      asm volatile("s_waitcnt vmcnt(6)" ::: "memory");
    else
      asm volatile("s_waitcnt vmcnt(0)" ::: "memory");
    __builtin_amdgcn_s_barrier();
    if (u + 2 < 12) {
      STAGE((u + 2) % 3, u + 2);
    }
    const char* Al = smem + (u % 3) * 49152;
#pragma unroll
    for (int kx = 0; kx < 3; ++kx) {
      bf16x8 aF[4], bF[4];
#pragma unroll
      for (int mb = 0; mb < 4; ++mb) aF[mb] = *(const bf16x8*)(Al + aoff[kx][mb]);
#pragma unroll
      for (int nb = 0; nb < 4; ++nb) bF[nb] = *(const bf16x8*)(Al + boff[kx][nb]);
#pragma unroll
      for (int mb = 0; mb < 4; ++mb)
#pragma unroll
        for (int nb = 0; nb < 4; ++nb)
          acc[mb][nb] = __builtin_amdgcn_mfma_f32_16x16x32_bf16(
              bF[nb], aF[mb], acc[mb][nb], 0, 0, 0);
    }
  }
#undef STAGE

  float sv[4] = {0, 0, 0, 0}, qv[4] = {0, 0, 0, 0};
#pragma unroll
  for (int mb = 0; mb < 4; ++mb) {
    int px = colA + mb * 16 + rl;
    int h = h0 + rowA;
    size_t base = (((size_t)b * 128 + h) * 128 + px) * 128;
#pragma unroll
    for (int nb = 0; nb < 4; ++nb) {
      int co0 = wn * 64 + nb * 16 + kg * 4;
      u16x4 pk;
#pragma unroll
      for (int j = 0; j < 4; ++j) {
        float v = acc[mb][nb][j];
        pk[j] = f2b(v);
        sv[nb] += v; qv[nb] += v * v;
      }
      *(u16x4*)(outu + base + co0) = pk;
    }
  }
  __syncthreads();
  float* sg = (float*)smem;
  if (tid < 16) sg[tid] = 0.f;
  __syncthreads();
#pragma unroll
  for (int nb = 0; nb < 4; ++nb) {
    float a = sv[nb], q = qv[nb];
#pragma unroll
    for (int o = 32; o > 0; o >>= 1) { a += __shfl_down(a, o); q += __shfl_down(q, o); }
    if (lane == 0) {
      int g = wn * 4 + nb;
      atomicAdd(&sg[g * 2 + 0], a);
      atomicAdd(&sg[g * 2 + 1], q);
    }
  }
  __syncthreads();
  if (tid < 16) partials[(size_t)nid * 16 + tid] = sg[tid];
}

// ---- reduce per-block partials [set][b][nper][16] -> stats[set][128] ------
__global__ void k_redstats(const float* __restrict__ partials, float* __restrict__ stats,
                           int nper) {
  int set = blockIdx.x;
  const float* p = partials + (size_t)set * 8 * nper * 16;
  float* st = stats + set * 128;
  int t = threadIdx.x;
  int o = t >> 2, j = t & 3;
  int b = o >> 4, slot = o & 15;
  int chunk = nper >> 2;
  float s = 0.f;
  for (int i = j * chunk; i < (j + 1) * chunk; ++i)
    s += p[((size_t)b * nper + i) * 16 + slot];
  s += __shfl_xor(s, 1);
  s += __shfl_xor(s, 2);
  if (j == 0) st[o] = s;
}

// ---- reduce merge partials (8192 x 16) -> stats2 --------------------------
__global__ void k_redstats2(const float* __restrict__ p2, float* __restrict__ st) {
  int o = blockIdx.x;
  int b = o >> 4, slot = o & 15;
  float s = 0.f;
  for (int i = threadIdx.x; i < 1024; i += 256)
    s += p2[((size_t)b * 1024 + i) * 16 + slot];
#pragma unroll
  for (int off = 32; off > 0; off >>= 1) s += __shfl_down(s, off);
  __shared__ float wsm[4];
  int lane = threadIdx.x & 63, wv = threadIdx.x >> 6;
  if (lane == 0) wsm[wv] = s;
  __syncthreads();
  if (threadIdx.x == 0) st[o] = wsm[0] + wsm[1] + wsm[2] + wsm[3];
}

// ---- merge NEXP fp8 experts ------------------------------------------------
template <int NEXP>
__global__ void k_merge(const unsigned char* __restrict__ c0,
                        const unsigned char* __restrict__ c1,
                        const unsigned char* __restrict__ c2,
                        const unsigned char* __restrict__ c3,
                        const float* __restrict__ st, const float* __restrict__ eg,
                        const float* __restrict__ eb, const float* __restrict__ wts,
                        unsigned short* __restrict__ merged,
                        const unsigned short* __restrict__ xp,
                        float* __restrict__ partials2, int e0, int flags) {
  __shared__ float sg[16];
  int tid = threadIdx.x;
  if (tid < 16) sg[tid] = 0.f;
  __syncthreads();
  size_t idx = ((size_t)blockIdx.x * 256 + tid) * 8;
  int co0 = (int)(idx & 127);
  size_t pix = idx >> 7;
  int w = (int)(pix & 127), h = (int)((pix >> 7) & 127), b = (int)(pix >> 14);
  int g = co0 >> 4;
  const float cnt = 16.f * 128.f * 128.f;
  int patch = (h >> 4) * 8 + (w >> 4);
  const unsigned char* cs[4] = {c0, c1, c2, c3};
  float a[8] = {0, 0, 0, 0, 0, 0, 0, 0};
#pragma unroll
  for (int k = 0; k < NEXP; ++k) {
    int e = e0 + k;
    float mean = st[e * 128 + (b * 8 + g) * 2] / cnt;
    float var = st[e * 128 + (b * 8 + g) * 2 + 1] / cnt - mean * mean;
    float rstd = rsqrtf(var + 1e-5f);
    float we = wts[patch * 8 + e];
    f32x4 g0 = *(const f32x4*)(eg + e * 128 + co0);
    f32x4 g1 = *(const f32x4*)(eg + e * 128 + co0 + 4);
    f32x4 b0 = *(const f32x4*)(eb + e * 128 + co0);
    f32x4 b1 = *(const f32x4*)(eb + e * 128 + co0 + 4);
    u32x2 cv = *(const u32x2*)(cs[k] + idx);
    f32x2 d0 = __builtin_amdgcn_cvt_pk_f32_fp8(cv[0], false);
    f32x2 d1 = __builtin_amdgcn_cvt_pk_f32_fp8(cv[0], true);
    f32x2 d2 = __builtin_amdgcn_cvt_pk_f32_fp8(cv[1], false);
    f32x2 d3 = __builtin_amdgcn_cvt_pk_f32_fp8(cv[1], true);
    float d[8] = {d0[0], d0[1], d1[0], d1[1], d2[0], d2[1], d3[0], d3[1]};
#pragma unroll
    for (int i = 0; i < 8; ++i) {
      float gi = (i < 4) ? g0[i] : g1[i - 4];
      float bi = (i < 4) ? b0[i] : b1[i - 4];
      float A = rstd * gi;
      float B = bi - mean * A;
      a[i] += we * fsilu(d[i] * A + B);
    }
  }
  if (flags & 1) {
    u16x8 mv = *(const u16x8*)(merged + idx);
#pragma unroll
    for (int i = 0; i < 8; ++i) a[i] += b2f(mv[i]);
  }
  u16x8 out;
  float s = 0.f, q = 0.f;
  if (flags & 2) {
    const unsigned short* xr =
        xp + (((size_t)b * 130 + h + 1) * 130 + (w + 1)) * 128 + co0;
    u16x8 xv = *(const u16x8*)xr;
#pragma unroll
    for (int i = 0; i < 8; ++i) {
      a[i] += b2f(xv[i]);
      out[i] = f2b(a[i]);
      float rv = b2f(out[i]);
      s += rv; q += rv * rv;
    }
  } else {
#pragma unroll
    for (int i = 0; i < 8; ++i) out[i] = f2b(a[i]);
  }
  *(u16x8*)(merged + idx) = out;
  if (flags & 2) {
    atomicAdd(&sg[g * 2 + 0], s);
    atomicAdd(&sg[g * 2 + 1], q);
    __syncthreads();
    if (tid < 16) partials2[(size_t)blockIdx.x * 16 + tid] = sg[tid];
  }
}

// ---- y = x + gamma*silu(gn(M)); bf16, in place into xpad -------------------
__global__ void k_ypass(const unsigned short* __restrict__ merged,
                        unsigned short* __restrict__ xp,
                        const float* __restrict__ st, const float* __restrict__ mg,
                        const float* __restrict__ mbv, const float* __restrict__ gptr) {
  size_t idx = ((size_t)blockIdx.x * 256 + threadIdx.x) * 8;
  int co0 = (int)(idx & 127);
  size_t pix = idx >> 7;
  int w = (int)(pix & 127), h = (int)((pix >> 7) & 127), b = (int)(pix >> 14);
  int g = co0 >> 4;
  const float cnt = 16.f * 128.f * 128.f;
  float mean = st[(b * 8 + g) * 2] / cnt;
  float var = st[(b * 8 + g) * 2 + 1] / cnt - mean * mean;
  float rstd = rsqrtf(var + 1e-5f);
  float gm = gptr[0];
  unsigned short* xr = xp + (((size_t)b * 130 + h + 1) * 130 + (w + 1)) * 128 + co0;
  u16x8 xv = *(const u16x8*)xr;
  u16x8 mv = *(const u16x8*)(merged + idx);
  u16x8 yv;
#pragma unroll
  for (int i = 0; i < 8; ++i) {
    float xf = b2f(xv[i]);
    float M = b2f(mv[i]);
    float xn = (M - mean) * rstd * mg[co0 + i] + mbv[co0 + i];
    yv[i] = f2b(xf + gm * fsilu(xn));
  }
  *(u16x8*)xr = yv;
}

// ---- final: out = silu(gn3(conv3)), NHWC bf16 -> NCHW f32 ------------------
__global__ void k_final(const __hip_bfloat16* __restrict__ conv, const float* __restrict__ st,
                        const float* __restrict__ pg, const float* __restrict__ pb,
                        float* __restrict__ out) {
  int bx = blockIdx.x;
  int wb = bx & 1, h = (bx >> 1) & 127, b = bx >> 8;
  int w0 = wb * 64;
  __shared__ float t[64][129];
  int tid = threadIdx.x;
  const float cnt = 16.f * 128.f * 128.f;
  const unsigned short* cu = (const unsigned short*)conv;
#pragma unroll
  for (int r = 0; r < 32; ++r) {
    int e2 = r * 256 + tid;
    int co = e2 & 127, wl = e2 >> 7;
    int g = co >> 4;
    float mean = st[(b * 8 + g) * 2] / cnt;
    float var = st[(b * 8 + g) * 2 + 1] / cnt - mean * mean;
    float rstd = rsqrtf(var + 1e-5f);
    float v = b2f(cu[(((size_t)b * 128 + h) * 128 + w0 + wl) * 128 + co]);
    float xn = (v - mean) * rstd * pg[co] + pb[co];
    t[wl][co] = fsilu(xn);
  }
  __syncthreads();
#pragma unroll
  for (int r = 0; r < 8; ++r) {
    int f = r * 256 + tid;
    int jb = f & 15, co = f >> 4;
    f32x4 o;
#pragma unroll
    for (int j = 0; j < 4; ++j) o[j] = t[jb * 4 + j][co];
    *(f32x4*)&out[(((size_t)b * 128 + co) * 128 + h) * 128 + w0 + jb * 4] = o;
  }
}

// ---------------------------------------------------------------------------
extern "C" void kernel_launch(void* const* d_in, const int* in_sizes, int n_in,
                              void* d_out, int out_size, void* d_ws, size_t ws_size,
                              hipStream_t stream) {
  const float* x        = (const float*)d_in[0];
  const float* expert_w = (const float*)d_in[1];
  const float* expert_g = (const float*)d_in[2];
  const float* expert_b = (const float*)d_in[3];
  const float* router_w = (const float*)d_in[4];
  const float* router_b = (const float*)d_in[5];
  const float* merge_g  = (const float*)d_in[6];
  const float* merge_b  = (const float*)d_in[7];
  const float* gamma    = (const float*)d_in[8];
  const float* post_w   = (const float*)d_in[9];
  const float* post_g   = (const float*)d_in[10];
  const float* post_b   = (const float*)d_in[11];

  char* ws = (char*)d_ws;
  float* wts            = (float*)(ws + 0);                  // 2048
  float* stats          = (float*)(ws + 2048);               // 5120
  float* partials       = (float*)(ws + 8192);               // 262144
  float* partials2      = (float*)(ws + 270336);             // 524288
  unsigned short* wtbp  = (unsigned short*)(ws + 794624);    // 294912
  unsigned char* wtb8   = (unsigned char*)(ws + 1089536);    // 1179648
  unsigned short* xpad  = (unsigned short*)(ws + 2269184);   // 34611200 (+8192 slack)
  unsigned char* xpad8  = (unsigned char*)(ws + 36888576);   // 17305600 (+4096 slack)
  const size_t BUFS = 54198272ull;
  const size_t FB = 16777216ull;
  const size_t NEED2 = BUFS + 2 * FB + 33554432ull;
  const size_t NEED4 = BUFS + 4 * FB + 33554432ull;
  int nbuf = (ws_size >= NEED4) ? 4 : 2;
  unsigned char* bufs0 = (unsigned char*)(ws + BUFS);
  unsigned short* merged = (unsigned short*)(ws + BUFS + (size_t)nbuf * FB);
  unsigned short* pbuf = (unsigned short*)(ws + BUFS);  // post conv out (reuse)
  if (ws_size < NEED2) {
    hipMemsetAsync(d_out, 0, (size_t)out_size * 4, stream);
    return;
  }

  k_zborder<<<17, 256, 0, stream>>>(xpad, xpad8);
  k_router<<<1, 64, 0, stream>>>(router_w, router_b, wts);
  k_build_xpad<<<4096, 256, 0, stream>>>(x, (__hip_bfloat16*)xpad, xpad8);
  k_build_w<<<576, 256, 0, stream>>>(post_w, (__hip_bfloat16*)wtbp);
  k_build_w8<<<4608, 256, 0, stream>>>(expert_w, wtb8);

  if (nbuf == 4) {
    for (int p = 0; p < 2; ++p) {
      k_conv8<4><<<2048, 512, 0, stream>>>(xpad8, wtb8 + (size_t)(p * 4) * 147456,
                                           bufs0, partials);
      k_redstats<<<4, 512, 0, stream>>>(partials, stats + p * 4 * 128, 64);
      int flags = (p > 0 ? 1 : 0) | (p == 1 ? 2 : 0);
      k_merge<4><<<8192, 256, 0, stream>>>(bufs0, bufs0 + FB, bufs0 + 2 * FB,
                                           bufs0 + 3 * FB, stats, expert_g, expert_b,
                                           wts, merged, xpad, partials2, p * 4, flags);
    }
  } else {
    for (int p = 0; p < 4; ++p) {
      k_conv8<2><<<1024, 512, 0, stream>>>(xpad8, wtb8 + (size_t)(p * 2) * 147456,
                                           bufs0, partials);
      k_redstats<<<2, 512, 0, stream>>>(partials, stats + p * 2 * 128, 64);
      int flags = (p > 0 ? 1 : 0) | (p == 3 ? 2 : 0);
      k_merge<2><<<8192, 256, 0, stream>>>(bufs0, bufs0 + FB, bufs0, bufs0 + FB,
                                           stats, expert_g, expert_b, wts, merged,
                                           xpad, partials2, p * 2, flags);
    }
  }
  k_redstats2<<<128, 256, 0, stream>>>(partials2, stats + 8 * 128);
  k_ypass<<<8192, 256, 0, stream>>>(merged, xpad, stats + 8 * 128, merge_g, merge_b, gamma);
  k_conv<<<512, 512, 0, stream>>>(xpad, wtbp, pbuf, partials);
  k_redstats<<<1, 512, 0, stream>>>(partials, stats + 9 * 128, 64);
  k_final<<<2048, 256, 0, stream>>>((const __hip_bfloat16*)pbuf, stats + 9 * 128,
                                    post_g, post_b, (float*)d_out);
}

// Round 13
// 396.291 us; speedup vs baseline: 1.1653x; 1.1289x over previous
//
#include <hip/hip_runtime.h>
#include <hip/hip_bf16.h>

// ---------------------------------------------------------------------------
// PCELayer. R13: expert convs on MX-scaled fp8 MFMA (16x16x128, scales=1.0),
// K-step = one full tap (128 ci). Per-pixel 128B ci-block, 16B chunks XOR-
// swizzled by (coord&7), pre-swizzled in global (G21). A-staging = linear
// 33KB copy (2 contiguous rows); A dbuf + B dbuf = 99KB LDS, 8 waves,
// plain syncthreads dbuf. Post conv: bf16 R11-structure (no setprio).
// ---------------------------------------------------------------------------

typedef __attribute__((ext_vector_type(8))) short bf16x8;
typedef __attribute__((ext_vector_type(4))) float f32x4;
typedef __attribute__((ext_vector_type(2))) float f32x2;
typedef __attribute__((ext_vector_type(8))) unsigned short u16x8;
typedef __attribute__((ext_vector_type(4))) unsigned short u16x4;
typedef __attribute__((ext_vector_type(2))) unsigned int u32x2;
typedef __attribute__((ext_vector_type(2))) int i32x2;
typedef __attribute__((ext_vector_type(4))) int i32x4;
typedef __attribute__((ext_vector_type(8))) int i32x8;

__device__ __forceinline__ float b2f(unsigned short u) {
  unsigned int v = ((unsigned int)u) << 16;
  return __builtin_bit_cast(float, v);
}
__device__ __forceinline__ unsigned short f2b(float f) {
  __hip_bfloat16 h = __float2bfloat16(f);
  return __builtin_bit_cast(unsigned short, h);
}
__device__ __forceinline__ float fsilu(float x) {
  float e = __expf(-x);
  return x * __builtin_amdgcn_rcpf(1.f + e);
}
__device__ __forceinline__ void gll16(const void* g, void* l) {
  __builtin_amdgcn_global_load_lds(
      (const __attribute__((address_space(1))) unsigned int*)g,
      (__attribute__((address_space(3))) unsigned int*)l, 16, 0, 0);
}
__device__ __forceinline__ unsigned char f2fp8(float v) {
  return (unsigned char)(__builtin_amdgcn_cvt_pk_fp8_f32(v, v, 0, false) & 0xff);
}

// ---- router ---------------------------------------------------------------
__global__ void k_router(const float* __restrict__ rw, const float* __restrict__ rb,
                         float* __restrict__ wts) {
  int t = threadIdx.x;
  if (t >= 64) return;
  int py = t >> 3, px = t & 7;
  float cy = (py + 0.5f) / 8.f, cx = (px + 0.5f) / 8.f;
  const float PI = 3.14159265358979323846f;
  float f[16];
#pragma unroll
  for (int k = 0; k < 4; ++k) {
    float fr = (float)(1 << k) * PI;
    f[k] = sinf(cy * fr); f[4 + k] = cosf(cy * fr);
    f[8 + k] = sinf(cx * fr); f[12 + k] = cosf(cx * fr);
  }
  float lg[8], mx = -1e30f;
#pragma unroll
  for (int e = 0; e < 8; ++e) {
    float a = rb[e];
#pragma unroll
    for (int k = 0; k < 16; ++k) a += f[k] * rw[k * 8 + e];
    lg[e] = a; mx = fmaxf(mx, a);
  }
  float s = 0.f;
#pragma unroll
  for (int e = 0; e < 8; ++e) { lg[e] = __expf(lg[e] - mx); s += lg[e]; }
  float inv = 1.f / s;
#pragma unroll
  for (int e = 0; e < 8; ++e) wts[t * 8 + e] = lg[e] * inv;
}

// ---- zero halo borders of xpad (bf16) and xpad8 (fp8, [pix][128]) ----------
__global__ void k_zborder(unsigned short* __restrict__ xpu,
                          unsigned char* __restrict__ xp8) {
  int idx = blockIdx.x * 256 + threadIdx.x;
  if (idx >= 8 * 516) return;
  int b = idx / 516, pxi = idx - b * 516;
  int r, c;
  if (pxi < 130)      { r = 0;   c = pxi; }
  else if (pxi < 260) { r = 129; c = pxi - 130; }
  else if (pxi < 388) { r = pxi - 260 + 1; c = 0; }
  else                { r = pxi - 388 + 1; c = 129; }
  size_t pix = (size_t)(b * 130 + r) * 130 + c;
  unsigned short* p = xpu + pix * 128;
#pragma unroll
  for (int j = 0; j < 16; ++j) *(u16x8*)(p + j * 8) = (u16x8)0;
  f32x4* q = (f32x4*)(xp8 + pix * 128);
#pragma unroll
  for (int j = 0; j < 8; ++j) q[j] = (f32x4)0.f;
}

// ---- x (NCHW f32) -> xpad bf16 [pix][128] + xpad8 fp8 [pix][128 swz] -------
__global__ void k_build_xpad(const float* __restrict__ x, __hip_bfloat16* __restrict__ xp,
                             unsigned char* __restrict__ xp8) {
  int bx = blockIdx.x;
  int wb = bx & 1, cib = (bx >> 1) & 1;
  int h = (bx >> 2) & 127, b = bx >> 9;
  int w0 = wb * 64, ci0 = cib * 64;
  __shared__ float t[64][65];
  int tid = threadIdx.x;
#pragma unroll
  for (int r = 0; r < 16; ++r) {
    int idx = r * 256 + tid;
    int i = idx >> 6, j = idx & 63;  // i: ci, j: w
    t[i][j] = x[(((size_t)b * 128 + ci0 + i) * 128 + h) * 128 + w0 + j];
  }
  __syncthreads();
  unsigned short* xpu = (unsigned short*)xp;
#pragma unroll
  for (int r = 0; r < 2; ++r) {
    int s = r * 256 + tid;          // 512 slots: 64 px x 8 ci-groups
    int px = s >> 3, cg = s & 7;
    int wpad = w0 + px + 1;
    size_t pixbase = ((size_t)b * 130 + h + 1) * 130 + wpad;
    float v[8];
    u16x8 bv;
#pragma unroll
    for (int k = 0; k < 8; ++k) { v[k] = t[cg * 8 + k][px]; bv[k] = f2b(v[k]); }
    int ci = ci0 + cg * 8;
    *(u16x8*)(xpu + pixbase * 128 + ci) = bv;
    // fp8: chunk c_log = ci>>4 -> c_phys = c_log ^ (wpad&7); 8B at (ci&8)
    int c_phys = (ci >> 4) ^ (wpad & 7);
    int pk0 = __builtin_amdgcn_cvt_pk_fp8_f32(v[0], v[1], 0, false);
    pk0 = __builtin_amdgcn_cvt_pk_fp8_f32(v[2], v[3], pk0, true);
    int pk1 = __builtin_amdgcn_cvt_pk_fp8_f32(v[4], v[5], 0, false);
    pk1 = __builtin_amdgcn_cvt_pk_fp8_f32(v[6], v[7], pk1, true);
    i32x2 pk = {pk0, pk1};
    *(i32x2*)(xp8 + pixbase * 128 + c_phys * 16 + (ci & 8)) = pk;
  }
}

// ---- post weights [co][ci][3][3] f32 -> [cc][tap][co][32ci] bf16 ----------
__global__ void k_build_w(const float* __restrict__ src, __hip_bfloat16* __restrict__ dst) {
  int o = blockIdx.x * 256 + threadIdx.x;
  if (o >= 147456) return;
  int cl = o & 31, co = (o >> 5) & 127;
  int r9 = o >> 12;  // 0..35
  int tp = r9 % 9, cc = r9 / 9;
  int ci = cc * 32 + cl;
  ((unsigned short*)dst)[o] = f2b(src[((size_t)co * 128 + ci) * 9 + tp]);
}

// ---- expert weights -> [e][tap][co][128 swz] fp8 ----------------------------
__global__ void k_build_w8(const float* __restrict__ src, unsigned char* __restrict__ dst) {
  int o = blockIdx.x * 256 + threadIdx.x;
  if (o >= 1179648) return;
  int e = o / 147456;
  int r = o - e * 147456;
  int tap = r >> 14;            // /16384
  int rr = r & 16383;
  int co = rr >> 7, byte = rr & 127;
  int c_phys = byte >> 4, j = byte & 15;
  int c_log = c_phys ^ (co & 7);
  int ci = c_log * 16 + j;
  dst[o] = f2fp8(src[(((size_t)e * 128 + co) * 128 + ci) * 9 + tap]);
}

// ---- expert conv3x3 MX-fp8 (K=128/tap), G experts fused --------------------
// 256px(2 rows) x 128co per block, 8 waves. A dbuf 2x33280 @0 (rows linear),
// B dbuf 2x16384 @66560. 9 units (taps). XCD k == image k.
template <int G>
__global__ __launch_bounds__(512, 2) void k_conv8(
    const unsigned char* __restrict__ xp8, const unsigned char* __restrict__ wt8,
    unsigned char* __restrict__ out8base, float* __restrict__ partials) {
  __shared__ __align__(16) char smem[99328];
  const int cpx = (G * 512) >> 3;
  const int nid = (blockIdx.x & 7) * cpx + (blockIdx.x >> 3);
  const int eg = nid & (G - 1);
  const int t0 = nid / G;
  const int b = t0 >> 6, rp = t0 & 63, h0 = rp * 2;
  const unsigned char* wt = wt8 + (size_t)eg * 147456;
  unsigned char* out8 = out8base + (size_t)eg * 16777216ull;

  const int tid = threadIdx.x;
  const int lane = tid & 63, wid = tid >> 6;
  const int wm = wid >> 1, wn = wid & 1;
  const int rl = lane & 15, kg = lane >> 4;
  const int rowA = wm >> 1;
  const int colA = (wm & 1) * 64;

  // LDS read offsets: 32B fragment = two b128 at chunks (2kg, 2kg+1) ^ (coord&7)
  int aoff[3][4][2], boff[4][2];
#pragma unroll
  for (int mb = 0; mb < 4; ++mb) {
    int col = colA + mb * 16 + rl;
#pragma unroll
    for (int kx = 0; kx < 3; ++kx) {
      int px = col + kx;
      int base = rowA * 16640 + px * 128;
      aoff[kx][mb][0] = base + ((2 * kg) ^ (px & 7)) * 16;
      aoff[kx][mb][1] = base + ((2 * kg + 1) ^ (px & 7)) * 16;
    }
  }
#pragma unroll
  for (int nb = 0; nb < 4; ++nb) {
    int co = wn * 64 + nb * 16 + rl;
    boff[nb][0] = 66560 + co * 128 + ((2 * kg) ^ (co & 7)) * 16;
    boff[nb][1] = 66560 + co * 128 + ((2 * kg + 1) ^ (co & 7)) * 16;
  }

  f32x4 acc[4][4] = {};

  // A: 2 contiguous rows = 33280 B = 2080 x16B slots, fully linear copy.
#define STGA(bi, ky_)                                                          \
  {                                                                            \
    const unsigned char* abase =                                               \
        xp8 + (size_t)(b * 130 + h0 + (ky_)) * 16640;                          \
    char* D = smem + (bi) * 33280;                                             \
    _Pragma("unroll")                                                          \
    for (int it = 0; it < 4; ++it)                                             \
      gll16(abase + (it * 512 + tid) * 16, D + (it * 512 + tid) * 16);         \
    if (tid < 32) gll16(abase + (2048 + tid) * 16, D + (2048 + tid) * 16);     \
  }
  // B: one tap = 16384 B = 1024 slots, linear.
#define STGB(bi, t_)                                                           \
  {                                                                            \
    const unsigned char* bbase = wt + (t_) * 16384;                            \
    char* D = smem + 66560 + (bi) * 16384;                                     \
    gll16(bbase + tid * 16, D + tid * 16);                                     \
    gll16(bbase + (512 + tid) * 16, D + (512 + tid) * 16);                     \
  }

  STGA(0, 0);
  STGB(0, 0);
#pragma unroll
  for (int t = 0; t < 9; ++t) {
    const int ky = t / 3, kx = t % 3;
    __syncthreads();
    if (t + 1 < 9) STGB((t + 1) & 1, t + 1);
    if (kx == 0 && ky < 2) STGA((ky + 1) & 1, ky + 1);
    const char* Al = smem + (ky & 1) * 33280;
    const int bsel = (t & 1) * 16384;
    i32x8 av[4], bv[4];
#pragma unroll
    for (int mb = 0; mb < 4; ++mb) {
      i32x4 lo = *(const i32x4*)(Al + aoff[kx][mb][0]);
      i32x4 hi = *(const i32x4*)(Al + aoff[kx][mb][1]);
      av[mb][0] = lo[0]; av[mb][1] = lo[1]; av[mb][2] = lo[2]; av[mb][3] = lo[3];
      av[mb][4] = hi[0]; av[mb][5] = hi[1]; av[mb][6] = hi[2]; av[mb][7] = hi[3];
    }
#pragma unroll
    for (int nb = 0; nb < 4; ++nb) {
      i32x4 lo = *(const i32x4*)(smem + bsel + boff[nb][0]);
      i32x4 hi = *(const i32x4*)(smem + bsel + boff[nb][1]);
      bv[nb][0] = lo[0]; bv[nb][1] = lo[1]; bv[nb][2] = lo[2]; bv[nb][3] = lo[3];
      bv[nb][4] = hi[0]; bv[nb][5] = hi[1]; bv[nb][6] = hi[2]; bv[nb][7] = hi[3];
    }
#pragma unroll
    for (int mb = 0; mb < 4; ++mb)
#pragma unroll
      for (int nb = 0; nb < 4; ++nb)
        acc[mb][nb] = __builtin_amdgcn_mfma_scale_f32_16x16x128_f8f6f4(
            bv[nb], av[mb], acc[mb][nb], 0, 0,
            0, 0x7F7F7F7F, 0, 0x7F7F7F7F);  // e8m0 0x7F = scale 1.0
  }
#undef STGA
#undef STGB

  // epilogue: fp8 pack + 4B stores, per-block GN partials
  float sv[4] = {0, 0, 0, 0}, qv[4] = {0, 0, 0, 0};
#pragma unroll
  for (int mb = 0; mb < 4; ++mb) {
    int px = colA + mb * 16 + rl;
    int h = h0 + rowA;
    size_t base = (((size_t)b * 128 + h) * 128 + px) * 128;
#pragma unroll
    for (int nb = 0; nb < 4; ++nb) {
      int co0 = wn * 64 + nb * 16 + kg * 4;
      f32x4 v = acc[mb][nb];
#pragma unroll
      for (int j = 0; j < 4; ++j) { sv[nb] += v[j]; qv[nb] += v[j] * v[j]; }
      int pk = __builtin_amdgcn_cvt_pk_fp8_f32(v[0], v[1], 0, false);
      pk = __builtin_amdgcn_cvt_pk_fp8_f32(v[2], v[3], pk, true);
      *(int*)(out8 + base + co0) = pk;
    }
  }
  __syncthreads();
  float* sg = (float*)smem;
  if (tid < 16) sg[tid] = 0.f;
  __syncthreads();
#pragma unroll
  for (int nb = 0; nb < 4; ++nb) {
    float a = sv[nb], q = qv[nb];
#pragma unroll
    for (int o = 32; o > 0; o >>= 1) { a += __shfl_down(a, o); q += __shfl_down(q, o); }
    if (lane == 0) {
      int g = wn * 4 + nb;
      atomicAdd(&sg[g * 2 + 0], a);
      atomicAdd(&sg[g * 2 + 1], q);
    }
  }
  __syncthreads();
  if (tid < 16)
    partials[((size_t)(eg * 8 + b) * 64 + rp) * 16 + tid] = sg[tid];
}

// ---- post conv3x3 bf16 (R11 structure, no setprio) --------------------------
__global__ __launch_bounds__(512, 2) void k_conv(
    const unsigned short* __restrict__ xpu, const unsigned short* __restrict__ wtu,
    unsigned short* __restrict__ outu, float* __restrict__ partials) {
  __shared__ __align__(16) char smem[90112];  // 2 x 45056
  const int nid = (blockIdx.x & 7) * 64 + (blockIdx.x >> 3);
  const int b = nid >> 6, rp = nid & 63, h0 = rp * 2;
  const int tid = threadIdx.x;
  const int lane = tid & 63, wid = tid >> 6;
  const int wm = wid >> 1, wn = wid & 1;
  const int rl = lane & 15, kg = lane >> 4;
  const int rowA = wm >> 1;
  const int colA = (wm & 1) * 64;

  int aoff[3][4], boff[3][4];
#pragma unroll
  for (int mb = 0; mb < 4; ++mb) {
    int col = colA + mb * 16 + rl;
#pragma unroll
    for (int kx = 0; kx < 3; ++kx) {
      int px = col + kx;
      aoff[kx][mb] = (rowA * 160 + px) * 64 + (kg ^ ((px >> 1) & 3)) * 16;
    }
  }
#pragma unroll
  for (int kx = 0; kx < 3; ++kx)
#pragma unroll
    for (int nb = 0; nb < 4; ++nb) {
      int co = wn * 64 + nb * 16 + rl;
      boff[kx][nb] = 20480 + ((kx * 128 + co) * 4 + (kg ^ ((co >> 1) & 3))) * 16;
    }

  int soff[6];
  bool isA[6];
#pragma unroll
  for (int it = 0; it < 6; ++it) {
    int s = it * 512 + tid;
    if (s < 1280) {
      int rw = (s >= 640) ? 1 : 0;
      int off = s - rw * 640;
      int px = off >> 2, q = off & 3;
      int qg = q ^ ((px >> 1) & 3);
      isA[it] = true;
      soff[it] = rw * 33280 + px * 256 + qg * 16;
    } else {
      int s2 = s - 1280;
      int tap = s2 >> 9, r3 = s2 & 511;
      int co = r3 >> 2, q = r3 & 3;
      int qg = q ^ ((co >> 1) & 3);
      isA[it] = false;
      soff[it] = tap * 8192 + co * 64 + qg * 16;
    }
  }

  f32x4 acc[4][4] = {};
  const char* xpb = (const char*)xpu;
  const char* wtb = (const char*)wtu;

#define STAGE(bi, u)                                                           \
  {                                                                            \
    const int cc_ = (u) / 3, ky_ = (u) % 3;                                    \
    char* D = smem + (bi) * 45056;                                             \
    const char* abase =                                                        \
        xpb + (size_t)(b * 130 + h0 + ky_) * 33280 + cc_ * 64;                 \
    const char* bbase = wtb + cc_ * 73728 + ky_ * 24576;                       \
    _Pragma("unroll")                                                          \
    for (int it = 0; it < 5; ++it)                                             \
      gll16((isA[it] ? abase : bbase) + soff[it], D + (it * 512 + tid) * 16);  \
    if (tid < 256) gll16(bbase + soff[5], D + (5 * 512 + tid) * 16);           \
  }

  STAGE(0, 0);
  for (int u = 0; u < 12; ++u) {
    const int cur = u & 1;
    __syncthreads();
    if (u + 1 < 12) STAGE(cur ^ 1, u + 1);
    const char* Al = smem + cur * 45056;
#pragma unroll
    for (int kx = 0; kx < 3; ++kx) {
      bf16x8 aF[4], bF[4];
#pragma unroll
      for (int mb = 0; mb < 4; ++mb) aF[mb] = *(const bf16x8*)(Al + aoff[kx][mb]);
#pragma unroll
      for (int nb = 0; nb < 4; ++nb) bF[nb] = *(const bf16x8*)(Al + boff[kx][nb]);
#pragma unroll
      for (int mb = 0; mb < 4; ++mb)
#pragma unroll
        for (int nb = 0; nb < 4; ++nb)
          acc[mb][nb] = __builtin_amdgcn_mfma_f32_16x16x32_bf16(
              bF[nb], aF[mb], acc[mb][nb], 0, 0, 0);
    }
  }
#undef STAGE

  float sv[4] = {0, 0, 0, 0}, qv[4] = {0, 0, 0, 0};
#pragma unroll
  for (int mb = 0; mb < 4; ++mb) {
    int px = colA + mb * 16 + rl;
    int h = h0 + rowA;
    size_t base = (((size_t)b * 128 + h) * 128 + px) * 128;
#pragma unroll
    for (int nb = 0; nb < 4; ++nb) {
      int co0 = wn * 64 + nb * 16 + kg * 4;
      u16x4 pk;
#pragma unroll
      for (int j = 0; j < 4; ++j) {
        float v = acc[mb][nb][j];
        pk[j] = f2b(v);
        sv[nb] += v; qv[nb] += v * v;
      }
      *(u16x4*)(outu + base + co0) = pk;
    }
  }
  __syncthreads();
  float* sg = (float*)smem;
  if (tid < 16) sg[tid] = 0.f;
  __syncthreads();
#pragma unroll
  for (int nb = 0; nb < 4; ++nb) {
    float a = sv[nb], q = qv[nb];
#pragma unroll
    for (int o = 32; o > 0; o >>= 1) { a += __shfl_down(a, o); q += __shfl_down(q, o); }
    if (lane == 0) {
      int g = wn * 4 + nb;
      atomicAdd(&sg[g * 2 + 0], a);
      atomicAdd(&sg[g * 2 + 1], q);
    }
  }
  __syncthreads();
  if (tid < 16) partials[(size_t)nid * 16 + tid] = sg[tid];
}

// ---- reduce per-block partials [set][b][nper][16] -> stats[set][128] ------
__global__ void k_redstats(const float* __restrict__ partials, float* __restrict__ stats,
                           int nper) {
  int set = blockIdx.x;
  const float* p = partials + (size_t)set * 8 * nper * 16;
  float* st = stats + set * 128;
  int t = threadIdx.x;
  int o = t >> 2, j = t & 3;
  int b = o >> 4, slot = o & 15;
  int chunk = nper >> 2;
  float s = 0.f;
  for (int i = j * chunk; i < (j + 1) * chunk; ++i)
    s += p[((size_t)b * nper + i) * 16 + slot];
  s += __shfl_xor(s, 1);
  s += __shfl_xor(s, 2);
  if (j == 0) st[o] = s;
}

// ---- reduce merge partials (8192 x 16) -> stats2 --------------------------
__global__ void k_redstats2(const float* __restrict__ p2, float* __restrict__ st) {
  int o = blockIdx.x;
  int b = o >> 4, slot = o & 15;
  float s = 0.f;
  for (int i = threadIdx.x; i < 1024; i += 256)
    s += p2[((size_t)b * 1024 + i) * 16 + slot];
#pragma unroll
  for (int off = 32; off > 0; off >>= 1) s += __shfl_down(s, off);
  __shared__ float wsm[4];
  int lane = threadIdx.x & 63, wv = threadIdx.x >> 6;
  if (lane == 0) wsm[wv] = s;
  __syncthreads();
  if (threadIdx.x == 0) st[o] = wsm[0] + wsm[1] + wsm[2] + wsm[3];
}

// ---- merge NEXP fp8 experts (conv outputs are PLAIN fp8 [pix][co]) ---------
template <int NEXP>
__global__ void k_merge(const unsigned char* __restrict__ c0,
                        const unsigned char* __restrict__ c1,
                        const unsigned char* __restrict__ c2,
                        const unsigned char* __restrict__ c3,
                        const float* __restrict__ st, const float* __restrict__ eg,
                        const float* __restrict__ eb, const float* __restrict__ wts,
                        unsigned short* __restrict__ merged,
                        const unsigned short* __restrict__ xp,
                        float* __restrict__ partials2, int e0, int flags) {
  __shared__ float sg[16];
  int tid = threadIdx.x;
  if (tid < 16) sg[tid] = 0.f;
  __syncthreads();
  size_t idx = ((size_t)blockIdx.x * 256 + tid) * 8;
  int co0 = (int)(idx & 127);
  size_t pix = idx >> 7;
  int w = (int)(pix & 127), h = (int)((pix >> 7) & 127), b = (int)(pix >> 14);
  int g = co0 >> 4;
  const float cnt = 16.f * 128.f * 128.f;
  int patch = (h >> 4) * 8 + (w >> 4);
  const unsigned char* cs[4] = {c0, c1, c2, c3};
  float a[8] = {0, 0, 0, 0, 0, 0, 0, 0};
#pragma unroll
  for (int k = 0; k < NEXP; ++k) {
    int e = e0 + k;
    float mean = st[e * 128 + (b * 8 + g) * 2] / cnt;
    float var = st[e * 128 + (b * 8 + g) * 2 + 1] / cnt - mean * mean;
    float rstd = rsqrtf(var + 1e-5f);
    float we = wts[patch * 8 + e];
    f32x4 g0 = *(const f32x4*)(eg + e * 128 + co0);
    f32x4 g1 = *(const f32x4*)(eg + e * 128 + co0 + 4);
    f32x4 b0 = *(const f32x4*)(eb + e * 128 + co0);
    f32x4 b1 = *(const f32x4*)(eb + e * 128 + co0 + 4);
    u32x2 cv = *(const u32x2*)(cs[k] + idx);
    f32x2 d0 = __builtin_amdgcn_cvt_pk_f32_fp8(cv[0], false);
    f32x2 d1 = __builtin_amdgcn_cvt_pk_f32_fp8(cv[0], true);
    f32x2 d2 = __builtin_amdgcn_cvt_pk_f32_fp8(cv[1], false);
    f32x2 d3 = __builtin_amdgcn_cvt_pk_f32_fp8(cv[1], true);
    float d[8] = {d0[0], d0[1], d1[0], d1[1], d2[0], d2[1], d3[0], d3[1]};
#pragma unroll
    for (int i = 0; i < 8; ++i) {
      float gi = (i < 4) ? g0[i] : g1[i - 4];
      float bi = (i < 4) ? b0[i] : b1[i - 4];
      float A = rstd * gi;
      float B = bi - mean * A;
      a[i] += we * fsilu(d[i] * A + B);
    }
  }
  if (flags & 1) {
    u16x8 mv = *(const u16x8*)(merged + idx);
#pragma unroll
    for (int i = 0; i < 8; ++i) a[i] += b2f(mv[i]);
  }
  u16x8 out;
  float s = 0.f, q = 0.f;
  if (flags & 2) {
    const unsigned short* xr =
        xp + (((size_t)b * 130 + h + 1) * 130 + (w + 1)) * 128 + co0;
    u16x8 xv = *(const u16x8*)xr;
#pragma unroll
    for (int i = 0; i < 8; ++i) {
      a[i] += b2f(xv[i]);
      out[i] = f2b(a[i]);
      float rv = b2f(out[i]);
      s += rv; q += rv * rv;
    }
  } else {
#pragma unroll
    for (int i = 0; i < 8; ++i) out[i] = f2b(a[i]);
  }
  *(u16x8*)(merged + idx) = out;
  if (flags & 2) {
    atomicAdd(&sg[g * 2 + 0], s);
    atomicAdd(&sg[g * 2 + 1], q);
    __syncthreads();
    if (tid < 16) partials2[(size_t)blockIdx.x * 16 + tid] = sg[tid];
  }
}

// ---- y = x + gamma*silu(gn(M)); bf16, in place into xpad -------------------
__global__ void k_ypass(const unsigned short* __restrict__ merged,
                        unsigned short* __restrict__ xp,
                        const float* __restrict__ st, const float* __restrict__ mg,
                        const float* __restrict__ mbv, const float* __restrict__ gptr) {
  size_t idx = ((size_t)blockIdx.x * 256 + threadIdx.x) * 8;
  int co0 = (int)(idx & 127);
  size_t pix = idx >> 7;
  int w = (int)(pix & 127), h = (int)((pix >> 7) & 127), b = (int)(pix >> 14);
  int g = co0 >> 4;
  const float cnt = 16.f * 128.f * 128.f;
  float mean = st[(b * 8 + g) * 2] / cnt;
  float var = st[(b * 8 + g) * 2 + 1] / cnt - mean * mean;
  float rstd = rsqrtf(var + 1e-5f);
  float gm = gptr[0];
  unsigned short* xr = xp + (((size_t)b * 130 + h + 1) * 130 + (w + 1)) * 128 + co0;
  u16x8 xv = *(const u16x8*)xr;
  u16x8 mv = *(const u16x8*)(merged + idx);
  u16x8 yv;
#pragma unroll
  for (int i = 0; i < 8; ++i) {
    float xf = b2f(xv[i]);
    float M = b2f(mv[i]);
    float xn = (M - mean) * rstd * mg[co0 + i] + mbv[co0 + i];
    yv[i] = f2b(xf + gm * fsilu(xn));
  }
  *(u16x8*)xr = yv;
}

// ---- final: out = silu(gn3(conv3)), NHWC bf16 -> NCHW f32 ------------------
__global__ void k_final(const __hip_bfloat16* __restrict__ conv, const float* __restrict__ st,
                        const float* __restrict__ pg, const float* __restrict__ pb,
                        float* __restrict__ out) {
  int bx = blockIdx.x;
  int wb = bx & 1, h = (bx >> 1) & 127, b = bx >> 8;
  int w0 = wb * 64;
  __shared__ float t[64][129];
  int tid = threadIdx.x;
  const float cnt = 16.f * 128.f * 128.f;
  const unsigned short* cu = (const unsigned short*)conv;
#pragma unroll
  for (int r = 0; r < 32; ++r) {
    int e2 = r * 256 + tid;
    int co = e2 & 127, wl = e2 >> 7;
    int g = co >> 4;
    float mean = st[(b * 8 + g) * 2] / cnt;
    float var = st[(b * 8 + g) * 2 + 1] / cnt - mean * mean;
    float rstd = rsqrtf(var + 1e-5f);
    float v = b2f(cu[(((size_t)b * 128 + h) * 128 + w0 + wl) * 128 + co]);
    float xn = (v - mean) * rstd * pg[co] + pb[co];
    t[wl][co] = fsilu(xn);
  }
  __syncthreads();
#pragma unroll
  for (int r = 0; r < 8; ++r) {
    int f = r * 256 + tid;
    int jb = f & 15, co = f >> 4;
    f32x4 o;
#pragma unroll
    for (int j = 0; j < 4; ++j) o[j] = t[jb * 4 + j][co];
    *(f32x4*)&out[(((size_t)b * 128 + co) * 128 + h) * 128 + w0 + jb * 4] = o;
  }
}

// ---------------------------------------------------------------------------
extern "C" void kernel_launch(void* const* d_in, const int* in_sizes, int n_in,
                              void* d_out, int out_size, void* d_ws, size_t ws_size,
                              hipStream_t stream) {
  const float* x        = (const float*)d_in[0];
  const float* expert_w = (const float*)d_in[1];
  const float* expert_g = (const float*)d_in[2];
  const float* expert_b = (const float*)d_in[3];
  const float* router_w = (const float*)d_in[4];
  const float* router_b = (const float*)d_in[5];
  const float* merge_g  = (const float*)d_in[6];
  const float* merge_b  = (const float*)d_in[7];
  const float* gamma    = (const float*)d_in[8];
  const float* post_w   = (const float*)d_in[9];
  const float* post_g   = (const float*)d_in[10];
  const float* post_b   = (const float*)d_in[11];

  char* ws = (char*)d_ws;
  float* wts            = (float*)(ws + 0);                  // 2048
  float* stats          = (float*)(ws + 2048);               // 5120
  float* partials       = (float*)(ws + 8192);               // 262144
  float* partials2      = (float*)(ws + 270336);             // 524288
  unsigned short* wtbp  = (unsigned short*)(ws + 794624);    // 294912
  unsigned char* wtb8   = (unsigned char*)(ws + 1089536);    // 1179648
  unsigned short* xpad  = (unsigned short*)(ws + 2269184);   // 34611200 (+8192 slack)
  unsigned char* xpad8  = (unsigned char*)(ws + 36888576);   // 17305600 (+4096 slack)
  const size_t BUFS = 54198272ull;
  const size_t FB = 16777216ull;
  const size_t NEED2 = BUFS + 2 * FB + 33554432ull;
  const size_t NEED4 = BUFS + 4 * FB + 33554432ull;
  int nbuf = (ws_size >= NEED4) ? 4 : 2;
  unsigned char* bufs0 = (unsigned char*)(ws + BUFS);
  unsigned short* merged = (unsigned short*)(ws + BUFS + (size_t)nbuf * FB);
  unsigned short* pbuf = (unsigned short*)(ws + BUFS);  // post conv out (reuse)
  if (ws_size < NEED2) {
    hipMemsetAsync(d_out, 0, (size_t)out_size * 4, stream);
    return;
  }

  k_zborder<<<17, 256, 0, stream>>>(xpad, xpad8);
  k_router<<<1, 64, 0, stream>>>(router_w, router_b, wts);
  k_build_xpad<<<4096, 256, 0, stream>>>(x, (__hip_bfloat16*)xpad, xpad8);
  k_build_w<<<576, 256, 0, stream>>>(post_w, (__hip_bfloat16*)wtbp);
  k_build_w8<<<4608, 256, 0, stream>>>(expert_w, wtb8);

  if (nbuf == 4) {
    for (int p = 0; p < 2; ++p) {
      k_conv8<4><<<2048, 512, 0, stream>>>(xpad8, wtb8 + (size_t)(p * 4) * 147456,
                                           bufs0, partials);
      k_redstats<<<4, 512, 0, stream>>>(partials, stats + p * 4 * 128, 64);
      int flags = (p > 0 ? 1 : 0) | (p == 1 ? 2 : 0);
      k_merge<4><<<8192, 256, 0, stream>>>(bufs0, bufs0 + FB, bufs0 + 2 * FB,
                                           bufs0 + 3 * FB, stats, expert_g, expert_b,
                                           wts, merged, xpad, partials2, p * 4, flags);
    }
  } else {
    for (int p = 0; p < 4; ++p) {
      k_conv8<2><<<1024, 512, 0, stream>>>(xpad8, wtb8 + (size_t)(p * 2) * 147456,
                                           bufs0, partials);
      k_redstats<<<2, 512, 0, stream>>>(partials, stats + p * 2 * 128, 64);
      int flags = (p > 0 ? 1 : 0) | (p == 3 ? 2 : 0);
      k_merge<2><<<8192, 256, 0, stream>>>(bufs0, bufs0 + FB, bufs0, bufs0 + FB,
                                           stats, expert_g, expert_b, wts, merged,
                                           xpad, partials2, p * 2, flags);
    }
  }
  k_redstats2<<<128, 256, 0, stream>>>(partials2, stats + 8 * 128);
  k_ypass<<<8192, 256, 0, stream>>>(merged, xpad, stats + 8 * 128, merge_g, merge_b, gamma);
  k_conv<<<512, 512, 0, stream>>>(xpad, wtbp, pbuf, partials);
  k_redstats<<<1, 512, 0, stream>>>(partials, stats + 9 * 128, 64);
  k_final<<<2048, 256, 0, stream>>>((const __hip_bfloat16*)pbuf, stats + 9 * 128,
                                    post_g, post_b, (float*)d_out);
}